// Round 7
// baseline (352.047 us; speedup 1.0000x reference)
//
#include <hip/hip_runtime.h>
#include <math.h>

#define L_SEQ   1024
#define DMODEL  2048
#define DINNER  4096
#define DSTATE  16
#define DTRANK  128
#define N_XZ    (2 * DINNER)            // 8192
#define N_XP    (DTRANK + 2 * DSTATE)   // 160
#define EPS_F   1e-5f
#define NCHUNK  32
#define TCH     32
#define SK_XP   16                      // split-K for xdbc GEMM

using bf16x8 = __attribute__((ext_vector_type(8))) short;
using f32x4  = __attribute__((ext_vector_type(4))) float;

__device__ __forceinline__ float silu_f(float v) {
    return v * (1.0f / (1.0f + __expf(-v)));
}
__device__ __forceinline__ float softplus_f(float v) {
    return (v > 15.0f) ? v : log1pf(__expf(v));
}
__device__ __forceinline__ unsigned short f2bf(float f) {
    unsigned b = __float_as_uint(f);
    return (unsigned short)((b + 0x7FFFu + ((b >> 16) & 1u)) >> 16);
}
__device__ __forceinline__ float bf2f(unsigned short u) {
    return __uint_as_float((unsigned)u << 16);
}

#define GLOAD_LDS(gp, lp) \
    __builtin_amdgcn_global_load_lds((const __attribute__((address_space(1))) void*)(gp), \
                                     (__attribute__((address_space(3))) void*)(lp), 16, 0, 0)

// ================= mega-prep: weight transposes + RMSNorm, one launch =================
// Blocked transpose: W[K][N] fp32 -> BTb[N/16][K/32][16][32] bf16 (the 1KB unit one
// gload_lds consumes). CTA tile 64n x 128k via LDS [64n][136k] ushort.
// Reads: 256B coalesced rows. Writes: one linear 1KB block per wave-instr, 4KB runs.
__device__ __forceinline__ void transpose_blocked(const float* __restrict__ W,
                                                  unsigned short* __restrict__ BTb,
                                                  int K, int N, int bx, int by,
                                                  unsigned short* Tb) {
    const int tid = threadIdx.x;
    const int n0 = bx * 64, k0 = by * 128;
    #pragma unroll
    for (int i = 0; i < 8; ++i) {
        const int r = i * 16 + (tid >> 4);      // k-row 0..127
        const int c = (tid & 15) * 4;           // n-col 0..60
        float4 v = *(const float4*)&W[(size_t)(k0 + r) * N + n0 + c];
        Tb[(c + 0) * 136 + r] = f2bf(v.x);
        Tb[(c + 1) * 136 + r] = f2bf(v.y);
        Tb[(c + 2) * 136 + r] = f2bf(v.z);
        Tb[(c + 3) * 136 + r] = f2bf(v.w);
    }
    __syncthreads();
    const int wave = tid >> 6, lane = tid & 63;
    const int kblocks = K >> 5;
    #pragma unroll
    for (int t = 0; t < 4; ++t) {
        const int ob = wave * 4 + t;            // 0..15
        const int nb = ob >> 2, kb = ob & 3;
        const int n = nb * 16 + (lane >> 2);    // local n 0..63
        const int k = kb * 32 + (lane & 3) * 8; // local k 0..127
        bf16x8 v = *(const bf16x8*)&Tb[n * 136 + k];
        // within-block offset = (n%16)*32 + (k%32) = lane*8
        const size_t blk = (size_t)(((n0 >> 4) + nb)) * kblocks + ((k0 >> 5) + kb);
        *(bf16x8*)&BTb[blk * 512 + (size_t)lane * 8] = v;
    }
}

// Row-major reg-transpose (W_dt -> BTdt for the k128 kernel). R2-verified.
__device__ __forceinline__ void transpose_fast(const float* __restrict__ W,
                                               unsigned short* __restrict__ BT,
                                               int K, int N, int bx, int by) {
    const int wave = threadIdx.x >> 6, lane = threadIdx.x & 63;
    const int lr = lane >> 3, lc = lane & 7;
    const int k0 = by * 128 + (wave >> 1) * 64 + lr * 8;
    const int n0 = bx * 128 + (wave & 1) * 64 + lc * 8;
    float v[8][8];
    #pragma unroll
    for (int j = 0; j < 8; ++j) {
        float4 a = *(const float4*)&W[(size_t)(k0 + j) * N + n0];
        float4 b = *(const float4*)&W[(size_t)(k0 + j) * N + n0 + 4];
        v[j][0] = a.x; v[j][1] = a.y; v[j][2] = a.z; v[j][3] = a.w;
        v[j][4] = b.x; v[j][5] = b.y; v[j][6] = b.z; v[j][7] = b.w;
    }
    #pragma unroll
    for (int i = 0; i < 8; ++i) {
        bf16x8 o;
        #pragma unroll
        for (int j = 0; j < 8; ++j) o[j] = (short)f2bf(v[j][i]);
        *(bf16x8*)&BT[(size_t)(n0 + i) * K + k0] = o;
    }
}

// Legacy LDS path (only W_xp: N=160; 2.5 MB, conflicts negligible)
__device__ __forceinline__ void transpose_body(const float* __restrict__ W,
                                               unsigned short* __restrict__ BT,
                                               int K, int N, int bx, int by,
                                               unsigned short (*Tl)[72]) {
    const int k0 = by * 64, n0 = bx * 32;
    const int kr = threadIdx.x >> 3;
    const int nc = (threadIdx.x & 7) * 4;
    float4 v0 = *(const float4*)&W[(size_t)(k0 + kr) * N + n0 + nc];
    float4 v1 = *(const float4*)&W[(size_t)(k0 + kr + 32) * N + n0 + nc];
    Tl[nc + 0][kr] = f2bf(v0.x); Tl[nc + 1][kr] = f2bf(v0.y);
    Tl[nc + 2][kr] = f2bf(v0.z); Tl[nc + 3][kr] = f2bf(v0.w);
    Tl[nc + 0][kr + 32] = f2bf(v1.x); Tl[nc + 1][kr + 32] = f2bf(v1.y);
    Tl[nc + 2][kr + 32] = f2bf(v1.z); Tl[nc + 3][kr + 32] = f2bf(v1.w);
    __syncthreads();
    const int n = threadIdx.x >> 3;
    const int k8 = (threadIdx.x & 7) * 8;
    *(bf16x8*)&BT[(size_t)(n0 + n) * K + k0 + k8] = *(const bf16x8*)&Tl[n][k8];
}

__global__ __launch_bounds__(256) void prep_kernel(const float* __restrict__ W_in,
                                                   const float* __restrict__ W_xp,
                                                   const float* __restrict__ W_dt,
                                                   const float* __restrict__ W_out,
                                                   const float* __restrict__ x,
                                                   const float* __restrict__ wn,
                                                   unsigned short* __restrict__ BT_in,
                                                   unsigned short* __restrict__ BTxp,
                                                   unsigned short* __restrict__ BTdt,
                                                   unsigned short* __restrict__ BT_out,
                                                   unsigned short* __restrict__ xn_bf) {
    __shared__ __align__(16) unsigned short Tb[64 * 136];
    __shared__ unsigned short Tl[32][72];
    __shared__ float red[4];
    int b = blockIdx.x;
    if (b < 2048) {                       // W_in blocked: 128 n-tiles x 16 k-tiles
        transpose_blocked(W_in, BT_in, DMODEL, N_XZ, b & 127, b >> 7, Tb);
    } else if (b < 3072) {                // W_out blocked: 32 n-tiles x 32 k-tiles
        b -= 2048;
        transpose_blocked(W_out, BT_out, DINNER, DMODEL, b & 31, b >> 5, Tb);
    } else if (b < 3104) {                // W_dt row-major: K=128, N=4096 (32 tiles)
        b -= 3072;
        transpose_fast(W_dt, BTdt, DTRANK, DINNER, b, 0);
    } else if (b < 3424) {                // W_xp legacy: K=4096, N=160
        b -= 3104;
        transpose_body(W_xp, BTxp, DINNER, N_XP, b % 5, b / 5, Tl);
    } else {                              // RMSNorm rows 0..1023
        const int row = b - 3424;
        const float4* xr = (const float4*)(x + (size_t)row * DMODEL);
        float ss = 0.f;
        float4 v0 = xr[threadIdx.x];
        float4 v1 = xr[threadIdx.x + 256];
        ss += v0.x*v0.x + v0.y*v0.y + v0.z*v0.z + v0.w*v0.w;
        ss += v1.x*v1.x + v1.y*v1.y + v1.z*v1.z + v1.w*v1.w;
        #pragma unroll
        for (int o = 32; o > 0; o >>= 1) ss += __shfl_down(ss, o);
        const int lane = threadIdx.x & 63, wv = threadIdx.x >> 6;
        if (lane == 0) red[wv] = ss;
        __syncthreads();
        if (threadIdx.x == 0) {
            float t = red[0] + red[1] + red[2] + red[3];
            red[0] = rsqrtf(t / (float)DMODEL + EPS_F);
        }
        __syncthreads();
        const float scale = red[0];
        const float4* wr = (const float4*)wn;
        float4 w0 = wr[threadIdx.x];
        float4 w1 = wr[threadIdx.x + 256];
        ushort4 o0, o1;
        o0.x = f2bf(v0.x * scale * w0.x); o0.y = f2bf(v0.y * scale * w0.y);
        o0.z = f2bf(v0.z * scale * w0.z); o0.w = f2bf(v0.w * scale * w0.w);
        o1.x = f2bf(v1.x * scale * w1.x); o1.y = f2bf(v1.y * scale * w1.y);
        o1.z = f2bf(v1.z * scale * w1.z); o1.w = f2bf(v1.w * scale * w1.w);
        unsigned short* outr = xn_bf + (size_t)row * DMODEL;
        *(ushort4*)&outr[threadIdx.x * 4] = o0;
        *(ushort4*)&outr[1024 + threadIdx.x * 4] = o1;
    }
}

// ================= bf16 MFMA GEMM, BK = KC*32 per barrier pair =================
// C(MxN) = A(MxK bf16) @ B^T. A row-major [M][K]. B operand: BLK=0 row-major BT[N][K];
// BLK=1 blocked BT[N/16][K/32][16][32] (1KB-contiguous gload_lds units).
// OUTM 0: bf16 plain   OUTM 2: fp32 split-K partial
// OUTM 3: fp32 v + aux[row*ldc+col]   OUTM 4: fp32 accumulate (Cf += v)
template <int BM, int BN, int KC, int OUTM, int BLK>
__global__ __launch_bounds__(256) void gemm_mfma_kernel(const unsigned short* __restrict__ A,
                                                        const unsigned short* __restrict__ BT,
                                                        void* __restrict__ Cv,
                                                        int K, int Kc, int ldc, int Ncols,
                                                        const float* __restrict__ aux) {
    constexpr int MT = BM / 32;
    constexpr int NT = BN / 32;
    __shared__ __align__(16) unsigned short Al[KC * BM * 32];
    __shared__ __align__(16) unsigned short Bl[KC * BN * 32];
    const int tid = threadIdx.x;
    const int lane = tid & 63, wave = tid >> 6;
    const int wm = wave >> 1, wn = wave & 1;
    const int bm = blockIdx.y * BM, bn = blockIdx.x * BN;
    const size_t koff = (size_t)blockIdx.z * Kc;
    float* Cf = (float*)Cv;
    if (OUTM == 2) Cf += (size_t)blockIdx.z * (size_t)gridDim.y * BM * ldc;
    const int sr = lane >> 2;
    const int sk = (((lane & 3) ^ ((sr >> 1) & 3))) * 8;
    const int fr = lane & 15;
    const int fq = lane >> 4;
    const int fsw = (fq ^ ((fr >> 1) & 3)) * 8;

    f32x4 acc[MT][NT];
    #pragma unroll
    for (int i = 0; i < MT; ++i)
        #pragma unroll
        for (int j = 0; j < NT; ++j)
            acc[i][j] = (f32x4){0.f, 0.f, 0.f, 0.f};

    for (int k0 = 0; k0 < Kc; k0 += 32 * KC) {
        #pragma unroll
        for (int p = 0; p < KC; ++p) {
            #pragma unroll
            for (int is = wave; is < BM / 16; is += 4)
                GLOAD_LDS(&A[(size_t)(bm + is * 16 + sr) * K + koff + k0 + p * 32 + sk],
                          &Al[p * BM * 32 + is * 512]);
            #pragma unroll
            for (int is = wave; is < BN / 16; is += 4) {
                if (BLK) {
                    const size_t blk = (size_t)((bn >> 4) + is) * (K >> 5)
                                     + ((koff + k0 + p * 32) >> 5);
                    GLOAD_LDS(&BT[blk * 512 + sr * 32 + sk],
                              &Bl[p * BN * 32 + is * 512]);
                } else {
                    GLOAD_LDS(&BT[(size_t)(bn + is * 16 + sr) * K + koff + k0 + p * 32 + sk],
                              &Bl[p * BN * 32 + is * 512]);
                }
            }
        }
        __syncthreads();
        #pragma unroll
        for (int p = 0; p < KC; ++p) {
            bf16x8 af[MT], bfr[NT];
            #pragma unroll
            for (int i = 0; i < MT; ++i)
                af[i] = *(const bf16x8*)&Al[p * BM * 32 + (wm * (BM / 2) + i * 16 + fr) * 32 + fsw];
            #pragma unroll
            for (int j = 0; j < NT; ++j)
                bfr[j] = *(const bf16x8*)&Bl[p * BN * 32 + (wn * (BN / 2) + j * 16 + fr) * 32 + fsw];
            #pragma unroll
            for (int i = 0; i < MT; ++i)
                #pragma unroll
                for (int j = 0; j < NT; ++j)
                    acc[i][j] = __builtin_amdgcn_mfma_f32_16x16x32_bf16(af[i], bfr[j], acc[i][j], 0, 0, 0);
        }
        __syncthreads();
    }

    #pragma unroll
    for (int i = 0; i < MT; ++i) {
        const int row = bm + wm * (BM / 2) + i * 16 + fq * 4;
        #pragma unroll
        for (int j = 0; j < NT; ++j) {
            const int col = bn + wn * (BN / 2) + j * 16 + fr;
            if (col < Ncols) {
                #pragma unroll
                for (int r = 0; r < 4; ++r) {
                    float v = acc[i][j][r];
                    if (OUTM == 0) {
                        ((unsigned short*)Cv)[(size_t)(row + r) * ldc + col] = f2bf(v);
                    } else if (OUTM == 2) {
                        Cf[(size_t)(row + r) * ldc + col] = v;
                    } else if (OUTM == 3) {
                        Cf[(size_t)(row + r) * ldc + col] =
                            v + aux[(size_t)(row + r) * ldc + col];
                    } else {
                        Cf[(size_t)(row + r) * ldc + col] += v;
                    }
                }
            }
        }
    }
}

// ============ K=128 GEMM, zero LDS: MFMA fragments loaded straight from L2/L3 ============
__global__ __launch_bounds__(256) void gemm_k128_softplus_kernel(
        const unsigned short* __restrict__ A,
        const unsigned short* __restrict__ BT,
        unsigned short* __restrict__ C,
        const float* __restrict__ bias) {
    const int lane = threadIdx.x & 63, wave = threadIdx.x >> 6;
    const int wm = wave >> 1, wn = wave & 1;
    const int fr = lane & 15, fq = lane >> 4;
    const int bm = blockIdx.y * 64, bn = blockIdx.x * 64;

    bf16x8 af[2][4], bfr[2][4];
    #pragma unroll
    for (int i = 0; i < 2; ++i) {
        const unsigned short* Ap = &A[(size_t)(bm + wm * 32 + i * 16 + fr) * DTRANK + fq * 8];
        #pragma unroll
        for (int kc = 0; kc < 4; ++kc) af[i][kc] = *(const bf16x8*)&Ap[kc * 32];
    }
    #pragma unroll
    for (int j = 0; j < 2; ++j) {
        const unsigned short* Bp = &BT[(size_t)(bn + wn * 32 + j * 16 + fr) * DTRANK + fq * 8];
        #pragma unroll
        for (int kc = 0; kc < 4; ++kc) bfr[j][kc] = *(const bf16x8*)&Bp[kc * 32];
    }

    f32x4 acc[2][2];
    #pragma unroll
    for (int i = 0; i < 2; ++i)
        #pragma unroll
        for (int j = 0; j < 2; ++j)
            acc[i][j] = (f32x4){0.f, 0.f, 0.f, 0.f};
    #pragma unroll
    for (int kc = 0; kc < 4; ++kc)
        #pragma unroll
        for (int i = 0; i < 2; ++i)
            #pragma unroll
            for (int j = 0; j < 2; ++j)
                acc[i][j] = __builtin_amdgcn_mfma_f32_16x16x32_bf16(af[i][kc], bfr[j][kc], acc[i][j], 0, 0, 0);

    #pragma unroll
    for (int i = 0; i < 2; ++i) {
        const int row = bm + wm * 32 + i * 16 + fq * 4;
        #pragma unroll
        for (int j = 0; j < 2; ++j) {
            const int col = bn + wn * 32 + j * 16 + fr;
            const float bc = bias[col];
            #pragma unroll
            for (int r = 0; r < 4; ++r)
                C[(size_t)(row + r) * DINNER + col] = f2bf(softplus_f(acc[i][j][r] + bc));
        }
    }
}

// ================= Depthwise causal conv (k=4) + SiLU, bf16 in/out, 8 ch/thread ==========
__global__ __launch_bounds__(256) void conv_silu_kernel(const unsigned short* __restrict__ xz_bf,
                                                        const float* __restrict__ cw,
                                                        const float* __restrict__ cb,
                                                        unsigned short* __restrict__ xs_bf) {
    const int idx = blockIdx.x * 256 + threadIdx.x;   // over L_SEQ * (DINNER/8)
    const int t = idx >> 9;
    const int c8 = (idx & 511) * 8;
    float acc[8];
    {
        float4 b0 = *(const float4*)&cb[c8];
        float4 b1 = *(const float4*)&cb[c8 + 4];
        acc[0] = b0.x; acc[1] = b0.y; acc[2] = b0.z; acc[3] = b0.w;
        acc[4] = b1.x; acc[5] = b1.y; acc[6] = b1.z; acc[7] = b1.w;
    }
    #pragma unroll
    for (int k = 0; k < 4; ++k) {
        const int tt = t + k - 3;
        if (tt >= 0) {
            bf16x8 xv = *(const bf16x8*)&xz_bf[(size_t)tt * N_XZ + c8];
            float4 w0 = *(const float4*)&cw[k * DINNER + c8];
            float4 w1 = *(const float4*)&cw[k * DINNER + c8 + 4];
            acc[0] = fmaf(bf2f((unsigned short)xv[0]), w0.x, acc[0]);
            acc[1] = fmaf(bf2f((unsigned short)xv[1]), w0.y, acc[1]);
            acc[2] = fmaf(bf2f((unsigned short)xv[2]), w0.z, acc[2]);
            acc[3] = fmaf(bf2f((unsigned short)xv[3]), w0.w, acc[3]);
            acc[4] = fmaf(bf2f((unsigned short)xv[4]), w1.x, acc[4]);
            acc[5] = fmaf(bf2f((unsigned short)xv[5]), w1.y, acc[5]);
            acc[6] = fmaf(bf2f((unsigned short)xv[6]), w1.z, acc[6]);
            acc[7] = fmaf(bf2f((unsigned short)xv[7]), w1.w, acc[7]);
        }
    }
    bf16x8 o;
    #pragma unroll
    for (int q = 0; q < 8; ++q) o[q] = (short)f2bf(silu_f(acc[q]));
    *(bf16x8*)&xs_bf[(size_t)t * DINNER + c8] = o;
}

// ================= reduce SK_XP split-K partials -> xdbc fp32 (+ bf16 dt cols) =================
__global__ __launch_bounds__(256) void reduce_sk_kernel(const float* __restrict__ part,
                                                        float* __restrict__ xdbc,
                                                        unsigned short* __restrict__ xdbc_dt) {
    const int i = (blockIdx.x * 256 + threadIdx.x) * 4;   // row*160 + col, 4-wide
    float4 s = make_float4(0.f, 0.f, 0.f, 0.f);
    #pragma unroll
    for (int c = 0; c < SK_XP; ++c) {
        float4 v = *(const float4*)&part[(size_t)c * (L_SEQ * N_XP) + i];
        s.x += v.x; s.y += v.y; s.z += v.z; s.w += v.w;
    }
    *(float4*)&xdbc[i] = s;
    const int col = i % N_XP;                              // multiple of 4; quad stays in-row
    if (col < DTRANK) {
        ushort4 o;
        o.x = f2bf(s.x); o.y = f2bf(s.y); o.z = f2bf(s.z); o.w = f2bf(s.w);
        *(ushort4*)&xdbc_dt[(i / N_XP) * DTRANK + col] = o;
    }
}

// ================= Selective scan, 3-pass chunked linear recurrence (bf16 inputs) ========
__global__ __launch_bounds__(256) void scan_pass1(const unsigned short* __restrict__ delta_bf,
                                                  const unsigned short* __restrict__ xs_bf,
                                                  const float* __restrict__ xdbc,
                                                  const float* __restrict__ A_log,
                                                  float* __restrict__ S,
                                                  float* __restrict__ sumdl) {
    __shared__ float BC[TCH][32];
    const int c = blockIdx.y;
    const int d = blockIdx.x * 256 + threadIdx.x;
    const int t0 = c * TCH;
    {
        const int tt = threadIdx.x >> 3, q = threadIdx.x & 7;
        *(float4*)&BC[tt][q * 4] =
            *(const float4*)&xdbc[(size_t)(t0 + tt) * N_XP + DTRANK + q * 4];
    }
    __syncthreads();
    float Aa[16];
    #pragma unroll
    for (int n = 0; n < 16; ++n) Aa[n] = -__expf(A_log[d * 16 + n]);
    float h[16];
    #pragma unroll
    for (int n = 0; n < 16; ++n) h[n] = 0.f;
    float sd = 0.f;
    for (int t = 0; t < TCH; ++t) {
        const float dl = bf2f(delta_bf[(size_t)(t0 + t) * DINNER + d]);
        const float u  = bf2f(xs_bf[(size_t)(t0 + t) * DINNER + d]);
        sd += dl;
        const float du = dl * u;
        #pragma unroll
        for (int n = 0; n < 16; ++n)
            h[n] = fmaf(h[n], __expf(dl * Aa[n]), du * BC[t][n]);
    }
    float* Sp = &S[((size_t)c * DINNER + d) * 16];
    #pragma unroll
    for (int n = 0; n < 16; n += 4)
        *(float4*)&Sp[n] = make_float4(h[n], h[n + 1], h[n + 2], h[n + 3]);
    sumdl[c * DINNER + d] = sd;
}

__global__ __launch_bounds__(256) void scan_pass2(const float* __restrict__ S,
                                                  const float* __restrict__ sumdl,
                                                  const float* __restrict__ A_log,
                                                  float* __restrict__ h0) {
    const int i = blockIdx.x * 256 + threadIdx.x;   // d*16 + n
    const int dd = i >> 4;
    const float A = -__expf(A_log[i]);
    float h = 0.f;
    #pragma unroll
    for (int c = 0; c < NCHUNK; ++c) {
        h0[(size_t)c * (DINNER * 16) + i] = h;
        h = h * __expf(A * sumdl[c * DINNER + dd]) + S[(size_t)c * (DINNER * 16) + i];
    }
}

__global__ __launch_bounds__(256) void scan_pass3(const unsigned short* __restrict__ delta_bf,
                                                  const unsigned short* __restrict__ xs_bf,
                                                  const float* __restrict__ xdbc,
                                                  const unsigned short* __restrict__ xz_bf,
                                                  const float* __restrict__ A_log,
                                                  const float* __restrict__ Dp,
                                                  const float* __restrict__ h0,
                                                  unsigned short* __restrict__ yg_bf) {
    __shared__ float BC[TCH][32];
    const int c = blockIdx.y;
    const int d = blockIdx.x * 256 + threadIdx.x;
    const int t0 = c * TCH;
    {
        const int tt = threadIdx.x >> 3, q = threadIdx.x & 7;
        *(float4*)&BC[tt][q * 4] =
            *(const float4*)&xdbc[(size_t)(t0 + tt) * N_XP + DTRANK + q * 4];
    }
    __syncthreads();
    float Aa[16];
    #pragma unroll
    for (int n = 0; n < 16; ++n) Aa[n] = -__expf(A_log[d * 16 + n]);
    float h[16];
    const float* h0p = &h0[(size_t)c * (DINNER * 16) + d * 16];
    #pragma unroll
    for (int n = 0; n < 16; n += 4) {
        float4 v = *(const float4*)&h0p[n];
        h[n] = v.x; h[n + 1] = v.y; h[n + 2] = v.z; h[n + 3] = v.w;
    }
    const float Dd = Dp[d];
    for (int t = 0; t < TCH; ++t) {
        const float dl = bf2f(delta_bf[(size_t)(t0 + t) * DINNER + d]);
        const float u  = bf2f(xs_bf[(size_t)(t0 + t) * DINNER + d]);
        const float du = dl * u;
        float y = 0.f;
        #pragma unroll
        for (int n = 0; n < 16; ++n) {
            h[n] = fmaf(h[n], __expf(dl * Aa[n]), du * BC[t][n]);
            y = fmaf(h[n], BC[t][16 + n], y);
        }
        const float res = bf2f(xz_bf[(size_t)(t0 + t) * N_XZ + DINNER + d]);
        yg_bf[(size_t)(t0 + t) * DINNER + d] = f2bf((y + u * Dd) * silu_f(res));
    }
}

extern "C" void kernel_launch(void* const* d_in, const int* in_sizes, int n_in,
                              void* d_out, int out_size, void* d_ws, size_t ws_size,
                              hipStream_t stream) {
    const float* x     = (const float*)d_in[0];
    const float* wn    = (const float*)d_in[1];
    const float* W_in  = (const float*)d_in[2];
    const float* cw    = (const float*)d_in[3];
    const float* cb    = (const float*)d_in[4];
    const float* W_xp  = (const float*)d_in[5];
    const float* W_dt  = (const float*)d_in[6];
    const float* b_dt  = (const float*)d_in[7];
    const float* A_log = (const float*)d_in[8];
    const float* Dp    = (const float*)d_in[9];
    const float* W_out = (const float*)d_in[10];
    float* out = (float*)d_out;

    float* ws = (float*)d_ws;                                     // offsets in floats
    unsigned short* xz_bf    = (unsigned short*)ws;               // [0, 4194304)
    unsigned short* xs_bf    = (unsigned short*)(ws + 4194304);   // [4194304, 6291456)
    unsigned short* yg_bf    = (unsigned short*)(ws + 6291456);   // [6291456, 8388608)
    unsigned short* delta_bf = (unsigned short*)(ws + 8388608);   // [8388608, 10485760)
    float*          part     = ws + 10485760;                     // step4: 2,621,440 f
    float*          S        = ws + 13107200;                     // 2,097,152 f
    float*          sumdl    = ws + 15204352;                     //   131,072 f
    float*          h0       = ws + 15335424;                     // 2,097,152 f
    float*          xdbc     = ws + 17432576;                     //   163,840 f
    unsigned short* xn_bf    = (unsigned short*)(ws + 17596416);  // 2,097,152 sh
    unsigned short* BTxp     = (unsigned short*)(ws + 18644992);  //   655,360 sh
    unsigned short* BTdt     = (unsigned short*)(ws + 18972672);  //   524,288 sh
    unsigned short* xdbc_dt  = (unsigned short*)(ws + 19234816);  //   131,072 sh
    unsigned short* BT_in    = (unsigned short*)(ws + 19300352);  // 16,777,216 sh (blocked)
    unsigned short* BT_out   = (unsigned short*)(ws + 27688960);  //  8,388,608 sh (blocked)
    // total: 31,883,264 f = 127.5 MB

    // 1. mega-prep: blocked transposes (W_in, W_out) + W_dt fast + W_xp legacy + RMSNorm
    prep_kernel<<<4448, 256, 0, stream>>>(W_in, W_xp, W_dt, W_out, x, wn,
                                          BT_in, BTxp, BTdt, BT_out, xn_bf);
    // 2. xz = xn @ W_in -> bf16  (128x128, blocked-B: 1KB-linear gload_lds)
    gemm_mfma_kernel<128, 128, 2, 0, 1><<<dim3(N_XZ / 128, L_SEQ / 128), 256, 0, stream>>>(
        xn_bf, BT_in, xz_bf, DMODEL, DMODEL, N_XZ, N_XZ, nullptr);
    // 3. conv + silu -> xs bf16 (8 ch/thread, 16B vector loads)
    conv_silu_kernel<<<(L_SEQ * DINNER / 8) / 256, 256, 0, stream>>>(xz_bf, cw, cb, xs_bf);
    // 4. xdbc = xs @ W_xp  (split-K x16, fp32 partials, row-major B)
    gemm_mfma_kernel<64, 64, 2, 2, 0><<<dim3(3, L_SEQ / 64, SK_XP), 256, 0, stream>>>(
        xs_bf, BTxp, part, DINNER, DINNER / SK_XP, N_XP, N_XP, nullptr);
    reduce_sk_kernel<<<(L_SEQ * N_XP / 4) / 256, 256, 0, stream>>>(part, xdbc, xdbc_dt);
    // 5. delta = softplus(xdbc_dt @ W_dt + b_dt) -> bf16  (zero-LDS direct-reg K=128 GEMM)
    gemm_k128_softplus_kernel<<<dim3(DINNER / 64, L_SEQ / 64), 256, 0, stream>>>(
        xdbc_dt, BTdt, delta_bf, b_dt);
    // 6. selective scan (3 passes, 32 chunks) + gate -> yg bf16
    scan_pass1<<<dim3(DINNER / 256, NCHUNK), 256, 0, stream>>>(delta_bf, xs_bf, xdbc, A_log, S, sumdl);
    scan_pass2<<<(DINNER * 16) / 256, 256, 0, stream>>>(S, sumdl, A_log, h0);
    scan_pass3<<<dim3(DINNER / 256, NCHUNK), 256, 0, stream>>>(delta_bf, xs_bf, xdbc, xz_bf,
                                                               A_log, Dp, h0, yg_bf);
    // 7. out = yg @ W_out + x  — two accumulate launches over K halves (no partials round-trip)
    //    A: k 0..2047, writes out = v + x   B: k 2048..4095, out += v
    gemm_mfma_kernel<64, 128, 2, 3, 1><<<dim3(DMODEL / 128, L_SEQ / 64), 256, 0, stream>>>(
        yg_bf, BT_out, out, DINNER, DINNER / 2, DMODEL, DMODEL, x);
    gemm_mfma_kernel<64, 128, 2, 4, 1><<<dim3(DMODEL / 128, L_SEQ / 64), 256, 0, stream>>>(
        yg_bf + 2048, BT_out + 64 * 512, out, DINNER, DINNER / 2, DMODEL, DMODEL, nullptr);
}

// Round 8
// 340.002 us; speedup vs baseline: 1.0354x; 1.0354x over previous
//
#include <hip/hip_runtime.h>
#include <math.h>

#define L_SEQ   1024
#define DMODEL  2048
#define DINNER  4096
#define DSTATE  16
#define DTRANK  128
#define N_XZ    (2 * DINNER)            // 8192
#define N_XP    (DTRANK + 2 * DSTATE)   // 160
#define EPS_F   1e-5f
#define NCHUNK  32
#define TCH     32
#define SK_XP   16                      // split-K for xdbc GEMM

using bf16x8 = __attribute__((ext_vector_type(8))) short;
using f32x4  = __attribute__((ext_vector_type(4))) float;

__device__ __forceinline__ float silu_f(float v) {
    return v * (1.0f / (1.0f + __expf(-v)));
}
__device__ __forceinline__ float softplus_f(float v) {
    return (v > 15.0f) ? v : log1pf(__expf(v));
}
__device__ __forceinline__ unsigned short f2bf(float f) {
    unsigned b = __float_as_uint(f);
    return (unsigned short)((b + 0x7FFFu + ((b >> 16) & 1u)) >> 16);
}
__device__ __forceinline__ float bf2f(unsigned short u) {
    return __uint_as_float((unsigned)u << 16);
}

#define GLOAD_LDS(gp, lp) \
    __builtin_amdgcn_global_load_lds((const __attribute__((address_space(1))) void*)(gp), \
                                     (__attribute__((address_space(3))) void*)(lp), 16, 0, 0)

// ================= mega-prep: weight transposes + RMSNorm, one launch =================
// fast2b: per-thread 2x(8x8) reg transpose, CTA 128k x 256n. Reads: 1KB contiguous per
// W row in a tight window (tests the DRAM read-granule theory). Writes: blocked layout
// BTb[N/16][K/32][16][32] — each wave's 512 stores densely cover an 8KB window, and the
// GEMM consumes each 1KB block with a single fully-linear global_load_lds. No LDS.
__device__ __forceinline__ void transpose_fast2b(const float* __restrict__ W,
                                                 unsigned short* __restrict__ BTb,
                                                 int K, int N, int bx, int by) {
    const int wave = threadIdx.x >> 6, lane = threadIdx.x & 63;
    const int lr = lane >> 3, lc = lane & 7;
    const int k0 = by * 128 + (wave >> 1) * 64 + lr * 8;
    const int nb = bx * 256 + (wave & 1) * 128;
    const int kblocks = K >> 5;
    float v[2][8][8];
    #pragma unroll
    for (int j = 0; j < 8; ++j) {
        #pragma unroll
        for (int p = 0; p < 2; ++p) {
            const float* rp = &W[(size_t)(k0 + j) * N + nb + p * 64 + lc * 8];
            float4 a = *(const float4*)rp;
            float4 b = *(const float4*)(rp + 4);
            v[p][j][0] = a.x; v[p][j][1] = a.y; v[p][j][2] = a.z; v[p][j][3] = a.w;
            v[p][j][4] = b.x; v[p][j][5] = b.y; v[p][j][6] = b.z; v[p][j][7] = b.w;
        }
    }
    #pragma unroll
    for (int p = 0; p < 2; ++p) {
        const int n0 = nb + p * 64 + lc * 8;
        #pragma unroll
        for (int i = 0; i < 8; ++i) {
            bf16x8 o;
            #pragma unroll
            for (int j = 0; j < 8; ++j) o[j] = (short)f2bf(v[p][j][i]);
            const int gn = n0 + i;
            const size_t blk = (size_t)(gn >> 4) * kblocks + (k0 >> 5);
            *(bf16x8*)&BTb[blk * 512 + (gn & 15) * 32 + (k0 & 31)] = o;
        }
    }
}

// Row-major reg-transpose (W_dt -> BTdt for the k128 kernel). R2-verified.
__device__ __forceinline__ void transpose_fast(const float* __restrict__ W,
                                               unsigned short* __restrict__ BT,
                                               int K, int N, int bx, int by) {
    const int wave = threadIdx.x >> 6, lane = threadIdx.x & 63;
    const int lr = lane >> 3, lc = lane & 7;
    const int k0 = by * 128 + (wave >> 1) * 64 + lr * 8;
    const int n0 = bx * 128 + (wave & 1) * 64 + lc * 8;
    float v[8][8];
    #pragma unroll
    for (int j = 0; j < 8; ++j) {
        float4 a = *(const float4*)&W[(size_t)(k0 + j) * N + n0];
        float4 b = *(const float4*)&W[(size_t)(k0 + j) * N + n0 + 4];
        v[j][0] = a.x; v[j][1] = a.y; v[j][2] = a.z; v[j][3] = a.w;
        v[j][4] = b.x; v[j][5] = b.y; v[j][6] = b.z; v[j][7] = b.w;
    }
    #pragma unroll
    for (int i = 0; i < 8; ++i) {
        bf16x8 o;
        #pragma unroll
        for (int j = 0; j < 8; ++j) o[j] = (short)f2bf(v[j][i]);
        *(bf16x8*)&BT[(size_t)(n0 + i) * K + k0] = o;
    }
}

// Legacy LDS path (only W_xp: N=160; 2.5 MB, conflicts negligible)
__device__ __forceinline__ void transpose_body(const float* __restrict__ W,
                                               unsigned short* __restrict__ BT,
                                               int K, int N, int bx, int by,
                                               unsigned short (*Tl)[72]) {
    const int k0 = by * 64, n0 = bx * 32;
    const int kr = threadIdx.x >> 3;
    const int nc = (threadIdx.x & 7) * 4;
    float4 v0 = *(const float4*)&W[(size_t)(k0 + kr) * N + n0 + nc];
    float4 v1 = *(const float4*)&W[(size_t)(k0 + kr + 32) * N + n0 + nc];
    Tl[nc + 0][kr] = f2bf(v0.x); Tl[nc + 1][kr] = f2bf(v0.y);
    Tl[nc + 2][kr] = f2bf(v0.z); Tl[nc + 3][kr] = f2bf(v0.w);
    Tl[nc + 0][kr + 32] = f2bf(v1.x); Tl[nc + 1][kr + 32] = f2bf(v1.y);
    Tl[nc + 2][kr + 32] = f2bf(v1.z); Tl[nc + 3][kr + 32] = f2bf(v1.w);
    __syncthreads();
    const int n = threadIdx.x >> 3;
    const int k8 = (threadIdx.x & 7) * 8;
    *(bf16x8*)&BT[(size_t)(n0 + n) * K + k0 + k8] = *(const bf16x8*)&Tl[n][k8];
}

__global__ __launch_bounds__(256) void prep_kernel(const float* __restrict__ W_in,
                                                   const float* __restrict__ W_xp,
                                                   const float* __restrict__ W_dt,
                                                   const float* __restrict__ W_out,
                                                   const float* __restrict__ x,
                                                   const float* __restrict__ wn,
                                                   unsigned short* __restrict__ BT_in,
                                                   unsigned short* __restrict__ BTxp,
                                                   unsigned short* __restrict__ BTdt,
                                                   unsigned short* __restrict__ BT_out,
                                                   unsigned short* __restrict__ xn_bf) {
    __shared__ unsigned short Tl[32][72];
    __shared__ float red[4];
    int b = blockIdx.x;
    if (b < 512) {                        // W_in: K=2048, N=8192 (16k x 32n tiles of 128x256)
        transpose_fast2b(W_in, BT_in, DMODEL, N_XZ, b & 31, b >> 5);
    } else if (b < 768) {                 // W_out: K=4096, N=2048 (32k x 8n tiles)
        b -= 512;
        transpose_fast2b(W_out, BT_out, DINNER, DMODEL, b & 7, b >> 3);
    } else if (b < 800) {                 // W_dt row-major: K=128, N=4096 (32 tiles)
        b -= 768;
        transpose_fast(W_dt, BTdt, DTRANK, DINNER, b, 0);
    } else if (b < 1120) {                // W_xp legacy: K=4096, N=160
        b -= 800;
        transpose_body(W_xp, BTxp, DINNER, N_XP, b % 5, b / 5, Tl);
    } else {                              // RMSNorm rows 0..1023
        const int row = b - 1120;
        const float4* xr = (const float4*)(x + (size_t)row * DMODEL);
        float ss = 0.f;
        float4 v0 = xr[threadIdx.x];
        float4 v1 = xr[threadIdx.x + 256];
        ss += v0.x*v0.x + v0.y*v0.y + v0.z*v0.z + v0.w*v0.w;
        ss += v1.x*v1.x + v1.y*v1.y + v1.z*v1.z + v1.w*v1.w;
        #pragma unroll
        for (int o = 32; o > 0; o >>= 1) ss += __shfl_down(ss, o);
        const int lane = threadIdx.x & 63, wv = threadIdx.x >> 6;
        if (lane == 0) red[wv] = ss;
        __syncthreads();
        if (threadIdx.x == 0) {
            float t = red[0] + red[1] + red[2] + red[3];
            red[0] = rsqrtf(t / (float)DMODEL + EPS_F);
        }
        __syncthreads();
        const float scale = red[0];
        const float4* wr = (const float4*)wn;
        float4 w0 = wr[threadIdx.x];
        float4 w1 = wr[threadIdx.x + 256];
        ushort4 o0, o1;
        o0.x = f2bf(v0.x * scale * w0.x); o0.y = f2bf(v0.y * scale * w0.y);
        o0.z = f2bf(v0.z * scale * w0.z); o0.w = f2bf(v0.w * scale * w0.w);
        o1.x = f2bf(v1.x * scale * w1.x); o1.y = f2bf(v1.y * scale * w1.y);
        o1.z = f2bf(v1.z * scale * w1.z); o1.w = f2bf(v1.w * scale * w1.w);
        unsigned short* outr = xn_bf + (size_t)row * DMODEL;
        *(ushort4*)&outr[threadIdx.x * 4] = o0;
        *(ushort4*)&outr[1024 + threadIdx.x * 4] = o1;
    }
}

// ================= bf16 MFMA GEMM, BK = KC*32 per barrier pair =================
// C(MxN) = A(MxK bf16) @ B^T. A row-major [M][K]. B operand: BLK=0 row-major BT[N][K];
// BLK=1 blocked BT[N/16][K/32][16][32] (1KB-contiguous gload_lds units).
// OUTM 0: bf16 plain   OUTM 2: fp32 split-K partial
template <int BM, int BN, int KC, int OUTM, int BLK>
__global__ __launch_bounds__(256) void gemm_mfma_kernel(const unsigned short* __restrict__ A,
                                                        const unsigned short* __restrict__ BT,
                                                        void* __restrict__ Cv,
                                                        int K, int Kc, int ldc, int Ncols,
                                                        const float* __restrict__ aux) {
    constexpr int MT = BM / 32;
    constexpr int NT = BN / 32;
    __shared__ __align__(16) unsigned short Al[KC * BM * 32];
    __shared__ __align__(16) unsigned short Bl[KC * BN * 32];
    const int tid = threadIdx.x;
    const int lane = tid & 63, wave = tid >> 6;
    const int wm = wave >> 1, wn = wave & 1;
    const int bm = blockIdx.y * BM, bn = blockIdx.x * BN;
    const size_t koff = (size_t)blockIdx.z * Kc;
    float* Cf = (float*)Cv;
    if (OUTM == 2) Cf += (size_t)blockIdx.z * (size_t)gridDim.y * BM * ldc;
    const int sr = lane >> 2;
    const int sk = (((lane & 3) ^ ((sr >> 1) & 3))) * 8;
    const int fr = lane & 15;
    const int fq = lane >> 4;
    const int fsw = (fq ^ ((fr >> 1) & 3)) * 8;

    f32x4 acc[MT][NT];
    #pragma unroll
    for (int i = 0; i < MT; ++i)
        #pragma unroll
        for (int j = 0; j < NT; ++j)
            acc[i][j] = (f32x4){0.f, 0.f, 0.f, 0.f};

    for (int k0 = 0; k0 < Kc; k0 += 32 * KC) {
        #pragma unroll
        for (int p = 0; p < KC; ++p) {
            #pragma unroll
            for (int is = wave; is < BM / 16; is += 4)
                GLOAD_LDS(&A[(size_t)(bm + is * 16 + sr) * K + koff + k0 + p * 32 + sk],
                          &Al[p * BM * 32 + is * 512]);
            #pragma unroll
            for (int is = wave; is < BN / 16; is += 4) {
                if (BLK) {
                    const size_t blk = (size_t)((bn >> 4) + is) * (K >> 5)
                                     + ((koff + k0 + p * 32) >> 5);
                    GLOAD_LDS(&BT[blk * 512 + sr * 32 + sk],
                              &Bl[p * BN * 32 + is * 512]);
                } else {
                    GLOAD_LDS(&BT[(size_t)(bn + is * 16 + sr) * K + koff + k0 + p * 32 + sk],
                              &Bl[p * BN * 32 + is * 512]);
                }
            }
        }
        __syncthreads();
        #pragma unroll
        for (int p = 0; p < KC; ++p) {
            bf16x8 af[MT], bfr[NT];
            #pragma unroll
            for (int i = 0; i < MT; ++i)
                af[i] = *(const bf16x8*)&Al[p * BM * 32 + (wm * (BM / 2) + i * 16 + fr) * 32 + fsw];
            #pragma unroll
            for (int j = 0; j < NT; ++j)
                bfr[j] = *(const bf16x8*)&Bl[p * BN * 32 + (wn * (BN / 2) + j * 16 + fr) * 32 + fsw];
            #pragma unroll
            for (int i = 0; i < MT; ++i)
                #pragma unroll
                for (int j = 0; j < NT; ++j)
                    acc[i][j] = __builtin_amdgcn_mfma_f32_16x16x32_bf16(af[i], bfr[j], acc[i][j], 0, 0, 0);
        }
        __syncthreads();
    }

    #pragma unroll
    for (int i = 0; i < MT; ++i) {
        const int row = bm + wm * (BM / 2) + i * 16 + fq * 4;
        #pragma unroll
        for (int j = 0; j < NT; ++j) {
            const int col = bn + wn * (BN / 2) + j * 16 + fr;
            if (col < Ncols) {
                #pragma unroll
                for (int r = 0; r < 4; ++r) {
                    float v = acc[i][j][r];
                    if (OUTM == 0) {
                        ((unsigned short*)Cv)[(size_t)(row + r) * ldc + col] = f2bf(v);
                    } else {
                        Cf[(size_t)(row + r) * ldc + col] = v;
                    }
                }
            }
        }
    }
}

// ============ K=128 GEMM, zero LDS: MFMA fragments loaded straight from L2/L3 ============
__global__ __launch_bounds__(256) void gemm_k128_softplus_kernel(
        const unsigned short* __restrict__ A,
        const unsigned short* __restrict__ BT,
        unsigned short* __restrict__ C,
        const float* __restrict__ bias) {
    const int lane = threadIdx.x & 63, wave = threadIdx.x >> 6;
    const int wm = wave >> 1, wn = wave & 1;
    const int fr = lane & 15, fq = lane >> 4;
    const int bm = blockIdx.y * 64, bn = blockIdx.x * 64;

    bf16x8 af[2][4], bfr[2][4];
    #pragma unroll
    for (int i = 0; i < 2; ++i) {
        const unsigned short* Ap = &A[(size_t)(bm + wm * 32 + i * 16 + fr) * DTRANK + fq * 8];
        #pragma unroll
        for (int kc = 0; kc < 4; ++kc) af[i][kc] = *(const bf16x8*)&Ap[kc * 32];
    }
    #pragma unroll
    for (int j = 0; j < 2; ++j) {
        const unsigned short* Bp = &BT[(size_t)(bn + wn * 32 + j * 16 + fr) * DTRANK + fq * 8];
        #pragma unroll
        for (int kc = 0; kc < 4; ++kc) bfr[j][kc] = *(const bf16x8*)&Bp[kc * 32];
    }

    f32x4 acc[2][2];
    #pragma unroll
    for (int i = 0; i < 2; ++i)
        #pragma unroll
        for (int j = 0; j < 2; ++j)
            acc[i][j] = (f32x4){0.f, 0.f, 0.f, 0.f};
    #pragma unroll
    for (int kc = 0; kc < 4; ++kc)
        #pragma unroll
        for (int i = 0; i < 2; ++i)
            #pragma unroll
            for (int j = 0; j < 2; ++j)
                acc[i][j] = __builtin_amdgcn_mfma_f32_16x16x32_bf16(af[i][kc], bfr[j][kc], acc[i][j], 0, 0, 0);

    #pragma unroll
    for (int i = 0; i < 2; ++i) {
        const int row = bm + wm * 32 + i * 16 + fq * 4;
        #pragma unroll
        for (int j = 0; j < 2; ++j) {
            const int col = bn + wn * 32 + j * 16 + fr;
            const float bc = bias[col];
            #pragma unroll
            for (int r = 0; r < 4; ++r)
                C[(size_t)(row + r) * DINNER + col] = f2bf(softplus_f(acc[i][j][r] + bc));
        }
    }
}

// ================= Depthwise causal conv (k=4) + SiLU, bf16 in/out, 8 ch/thread ==========
__global__ __launch_bounds__(256) void conv_silu_kernel(const unsigned short* __restrict__ xz_bf,
                                                        const float* __restrict__ cw,
                                                        const float* __restrict__ cb,
                                                        unsigned short* __restrict__ xs_bf) {
    const int idx = blockIdx.x * 256 + threadIdx.x;   // over L_SEQ * (DINNER/8)
    const int t = idx >> 9;
    const int c8 = (idx & 511) * 8;
    float acc[8];
    {
        float4 b0 = *(const float4*)&cb[c8];
        float4 b1 = *(const float4*)&cb[c8 + 4];
        acc[0] = b0.x; acc[1] = b0.y; acc[2] = b0.z; acc[3] = b0.w;
        acc[4] = b1.x; acc[5] = b1.y; acc[6] = b1.z; acc[7] = b1.w;
    }
    #pragma unroll
    for (int k = 0; k < 4; ++k) {
        const int tt = t + k - 3;
        if (tt >= 0) {
            bf16x8 xv = *(const bf16x8*)&xz_bf[(size_t)tt * N_XZ + c8];
            float4 w0 = *(const float4*)&cw[k * DINNER + c8];
            float4 w1 = *(const float4*)&cw[k * DINNER + c8 + 4];
            acc[0] = fmaf(bf2f((unsigned short)xv[0]), w0.x, acc[0]);
            acc[1] = fmaf(bf2f((unsigned short)xv[1]), w0.y, acc[1]);
            acc[2] = fmaf(bf2f((unsigned short)xv[2]), w0.z, acc[2]);
            acc[3] = fmaf(bf2f((unsigned short)xv[3]), w0.w, acc[3]);
            acc[4] = fmaf(bf2f((unsigned short)xv[4]), w1.x, acc[4]);
            acc[5] = fmaf(bf2f((unsigned short)xv[5]), w1.y, acc[5]);
            acc[6] = fmaf(bf2f((unsigned short)xv[6]), w1.z, acc[6]);
            acc[7] = fmaf(bf2f((unsigned short)xv[7]), w1.w, acc[7]);
        }
    }
    bf16x8 o;
    #pragma unroll
    for (int q = 0; q < 8; ++q) o[q] = (short)f2bf(silu_f(acc[q]));
    *(bf16x8*)&xs_bf[(size_t)t * DINNER + c8] = o;
}

// ================= reduce SK_XP split-K partials -> xdbc fp32 (+ bf16 dt cols) =================
__global__ __launch_bounds__(256) void reduce_sk_kernel(const float* __restrict__ part,
                                                        float* __restrict__ xdbc,
                                                        unsigned short* __restrict__ xdbc_dt) {
    const int i = (blockIdx.x * 256 + threadIdx.x) * 4;   // row*160 + col, 4-wide
    float4 s = make_float4(0.f, 0.f, 0.f, 0.f);
    #pragma unroll
    for (int c = 0; c < SK_XP; ++c) {
        float4 v = *(const float4*)&part[(size_t)c * (L_SEQ * N_XP) + i];
        s.x += v.x; s.y += v.y; s.z += v.z; s.w += v.w;
    }
    *(float4*)&xdbc[i] = s;
    const int col = i % N_XP;                              // multiple of 4; quad stays in-row
    if (col < DTRANK) {
        ushort4 o;
        o.x = f2bf(s.x); o.y = f2bf(s.y); o.z = f2bf(s.z); o.w = f2bf(s.w);
        *(ushort4*)&xdbc_dt[(i / N_XP) * DTRANK + col] = o;
    }
}

// ============ reduce 2 split-K partials + residual x -> out fp32 (step 7 tail) ============
__global__ __launch_bounds__(256) void reduce2_res_kernel(const float* __restrict__ part,
                                                          const float* __restrict__ x,
                                                          float* __restrict__ out) {
    const size_t i = ((size_t)blockIdx.x * 256 + threadIdx.x) * 4;
    float4 a = *(const float4*)&part[i];
    float4 b = *(const float4*)&part[(size_t)L_SEQ * DMODEL + i];
    float4 r = *(const float4*)&x[i];
    float4 o;
    o.x = a.x + b.x + r.x;
    o.y = a.y + b.y + r.y;
    o.z = a.z + b.z + r.z;
    o.w = a.w + b.w + r.w;
    *(float4*)&out[i] = o;
}

// ================= Selective scan, 3-pass chunked linear recurrence (bf16 inputs) ========
__global__ __launch_bounds__(256) void scan_pass1(const unsigned short* __restrict__ delta_bf,
                                                  const unsigned short* __restrict__ xs_bf,
                                                  const float* __restrict__ xdbc,
                                                  const float* __restrict__ A_log,
                                                  float* __restrict__ S,
                                                  float* __restrict__ sumdl) {
    __shared__ float BC[TCH][32];
    const int c = blockIdx.y;
    const int d = blockIdx.x * 256 + threadIdx.x;
    const int t0 = c * TCH;
    {
        const int tt = threadIdx.x >> 3, q = threadIdx.x & 7;
        *(float4*)&BC[tt][q * 4] =
            *(const float4*)&xdbc[(size_t)(t0 + tt) * N_XP + DTRANK + q * 4];
    }
    __syncthreads();
    float Aa[16];
    #pragma unroll
    for (int n = 0; n < 16; ++n) Aa[n] = -__expf(A_log[d * 16 + n]);
    float h[16];
    #pragma unroll
    for (int n = 0; n < 16; ++n) h[n] = 0.f;
    float sd = 0.f;
    for (int t = 0; t < TCH; ++t) {
        const float dl = bf2f(delta_bf[(size_t)(t0 + t) * DINNER + d]);
        const float u  = bf2f(xs_bf[(size_t)(t0 + t) * DINNER + d]);
        sd += dl;
        const float du = dl * u;
        #pragma unroll
        for (int n = 0; n < 16; ++n)
            h[n] = fmaf(h[n], __expf(dl * Aa[n]), du * BC[t][n]);
    }
    float* Sp = &S[((size_t)c * DINNER + d) * 16];
    #pragma unroll
    for (int n = 0; n < 16; n += 4)
        *(float4*)&Sp[n] = make_float4(h[n], h[n + 1], h[n + 2], h[n + 3]);
    sumdl[c * DINNER + d] = sd;
}

__global__ __launch_bounds__(256) void scan_pass2(const float* __restrict__ S,
                                                  const float* __restrict__ sumdl,
                                                  const float* __restrict__ A_log,
                                                  float* __restrict__ h0) {
    const int i = blockIdx.x * 256 + threadIdx.x;   // d*16 + n
    const int dd = i >> 4;
    const float A = -__expf(A_log[i]);
    float h = 0.f;
    #pragma unroll
    for (int c = 0; c < NCHUNK; ++c) {
        h0[(size_t)c * (DINNER * 16) + i] = h;
        h = h * __expf(A * sumdl[c * DINNER + dd]) + S[(size_t)c * (DINNER * 16) + i];
    }
}

__global__ __launch_bounds__(256) void scan_pass3(const unsigned short* __restrict__ delta_bf,
                                                  const unsigned short* __restrict__ xs_bf,
                                                  const float* __restrict__ xdbc,
                                                  const unsigned short* __restrict__ xz_bf,
                                                  const float* __restrict__ A_log,
                                                  const float* __restrict__ Dp,
                                                  const float* __restrict__ h0,
                                                  unsigned short* __restrict__ yg_bf) {
    __shared__ float BC[TCH][32];
    const int c = blockIdx.y;
    const int d = blockIdx.x * 256 + threadIdx.x;
    const int t0 = c * TCH;
    {
        const int tt = threadIdx.x >> 3, q = threadIdx.x & 7;
        *(float4*)&BC[tt][q * 4] =
            *(const float4*)&xdbc[(size_t)(t0 + tt) * N_XP + DTRANK + q * 4];
    }
    __syncthreads();
    float Aa[16];
    #pragma unroll
    for (int n = 0; n < 16; ++n) Aa[n] = -__expf(A_log[d * 16 + n]);
    float h[16];
    const float* h0p = &h0[(size_t)c * (DINNER * 16) + d * 16];
    #pragma unroll
    for (int n = 0; n < 16; n += 4) {
        float4 v = *(const float4*)&h0p[n];
        h[n] = v.x; h[n + 1] = v.y; h[n + 2] = v.z; h[n + 3] = v.w;
    }
    const float Dd = Dp[d];
    for (int t = 0; t < TCH; ++t) {
        const float dl = bf2f(delta_bf[(size_t)(t0 + t) * DINNER + d]);
        const float u  = bf2f(xs_bf[(size_t)(t0 + t) * DINNER + d]);
        const float du = dl * u;
        float y = 0.f;
        #pragma unroll
        for (int n = 0; n < 16; ++n) {
            h[n] = fmaf(h[n], __expf(dl * Aa[n]), du * BC[t][n]);
            y = fmaf(h[n], BC[t][16 + n], y);
        }
        const float res = bf2f(xz_bf[(size_t)(t0 + t) * N_XZ + DINNER + d]);
        yg_bf[(size_t)(t0 + t) * DINNER + d] = f2bf((y + u * Dd) * silu_f(res));
    }
}

extern "C" void kernel_launch(void* const* d_in, const int* in_sizes, int n_in,
                              void* d_out, int out_size, void* d_ws, size_t ws_size,
                              hipStream_t stream) {
    const float* x     = (const float*)d_in[0];
    const float* wn    = (const float*)d_in[1];
    const float* W_in  = (const float*)d_in[2];
    const float* cw    = (const float*)d_in[3];
    const float* cb    = (const float*)d_in[4];
    const float* W_xp  = (const float*)d_in[5];
    const float* W_dt  = (const float*)d_in[6];
    const float* b_dt  = (const float*)d_in[7];
    const float* A_log = (const float*)d_in[8];
    const float* Dp    = (const float*)d_in[9];
    const float* W_out = (const float*)d_in[10];
    float* out = (float*)d_out;

    float* ws = (float*)d_ws;                                     // offsets in floats
    unsigned short* xz_bf    = (unsigned short*)ws;               // [0, 4194304)
    unsigned short* xs_bf    = (unsigned short*)(ws + 4194304);   // [4194304, 6291456)
    unsigned short* yg_bf    = (unsigned short*)(ws + 6291456);   // [6291456, 8388608)
    unsigned short* delta_bf = (unsigned short*)(ws + 8388608);   // [8388608, 10485760)
    float*          part     = ws + 10485760;                     // step4: 2,621,440 f; step7 reuse: 4,194,304 f (spills into dead S)
    float*          S        = ws + 13107200;                     // 2,097,152 f
    float*          sumdl    = ws + 15204352;                     //   131,072 f
    float*          h0       = ws + 15335424;                     // 2,097,152 f
    float*          xdbc     = ws + 17432576;                     //   163,840 f
    unsigned short* xn_bf    = (unsigned short*)(ws + 17596416);  // 2,097,152 sh
    unsigned short* BTxp     = (unsigned short*)(ws + 18644992);  //   655,360 sh
    unsigned short* BTdt     = (unsigned short*)(ws + 18972672);  //   524,288 sh
    unsigned short* xdbc_dt  = (unsigned short*)(ws + 19234816);  //   131,072 sh
    unsigned short* BT_in    = (unsigned short*)(ws + 19300352);  // 16,777,216 sh (blocked)
    unsigned short* BT_out   = (unsigned short*)(ws + 27688960);  //  8,388,608 sh (blocked)
    // total: 31,883,264 f = 127.5 MB

    // 1. mega-prep: fast2b blocked transposes (W_in, W_out) + W_dt fast + W_xp legacy + RMSNorm
    prep_kernel<<<2144, 256, 0, stream>>>(W_in, W_xp, W_dt, W_out, x, wn,
                                          BT_in, BTxp, BTdt, BT_out, xn_bf);
    // 2. xz = xn @ W_in -> bf16  (128x128, blocked-B: 1KB-linear gload_lds)
    gemm_mfma_kernel<128, 128, 2, 0, 1><<<dim3(N_XZ / 128, L_SEQ / 128), 256, 0, stream>>>(
        xn_bf, BT_in, xz_bf, DMODEL, DMODEL, N_XZ, N_XZ, nullptr);
    // 3. conv + silu -> xs bf16 (8 ch/thread, 16B vector loads)
    conv_silu_kernel<<<(L_SEQ * DINNER / 8) / 256, 256, 0, stream>>>(xz_bf, cw, cb, xs_bf);
    // 4. xdbc = xs @ W_xp  (split-K x16, fp32 partials, row-major B)
    gemm_mfma_kernel<64, 64, 2, 2, 0><<<dim3(3, L_SEQ / 64, SK_XP), 256, 0, stream>>>(
        xs_bf, BTxp, part, DINNER, DINNER / SK_XP, N_XP, N_XP, nullptr);
    reduce_sk_kernel<<<(L_SEQ * N_XP / 4) / 256, 256, 0, stream>>>(part, xdbc, xdbc_dt);
    // 5. delta = softplus(xdbc_dt @ W_dt + b_dt) -> bf16  (zero-LDS direct-reg K=128 GEMM)
    gemm_k128_softplus_kernel<<<dim3(DINNER / 64, L_SEQ / 64), 256, 0, stream>>>(
        xdbc_dt, BTdt, delta_bf, b_dt);
    // 6. selective scan (3 passes, 32 chunks) + gate -> yg bf16
    scan_pass1<<<dim3(DINNER / 256, NCHUNK), 256, 0, stream>>>(delta_bf, xs_bf, xdbc, A_log, S, sumdl);
    scan_pass2<<<(DINNER * 16) / 256, 256, 0, stream>>>(S, sumdl, A_log, h0);
    scan_pass3<<<dim3(DINNER / 256, NCHUNK), 256, 0, stream>>>(delta_bf, xs_bf, xdbc, xz_bf,
                                                               A_log, Dp, h0, yg_bf);
    // 7. out = yg @ W_out (64x128, blocked-B, split-K x2 -> 512 blocks = 2/CU, fp32 partials)
    gemm_mfma_kernel<64, 128, 2, 2, 1><<<dim3(DMODEL / 128, L_SEQ / 64, 2), 256, 0, stream>>>(
        yg_bf, BT_out, part, DINNER, DINNER / 2, DMODEL, DMODEL, nullptr);
    //    reduce partials + residual x -> out
    reduce2_res_kernel<<<(L_SEQ * DMODEL) / 1024, 256, 0, stream>>>(part, x, out);
}

// Round 9
// 331.309 us; speedup vs baseline: 1.0626x; 1.0262x over previous
//
#include <hip/hip_runtime.h>
#include <math.h>

#define L_SEQ   1024
#define DMODEL  2048
#define DINNER  4096
#define DSTATE  16
#define DTRANK  128
#define N_XZ    (2 * DINNER)            // 8192
#define N_XP    (DTRANK + 2 * DSTATE)   // 160
#define EPS_F   1e-5f
#define NCHUNK  32
#define TCH     32
#define SK_XP   16                      // split-K for xdbc GEMM

using bf16x8 = __attribute__((ext_vector_type(8))) short;
using f32x4  = __attribute__((ext_vector_type(4))) float;

__device__ __forceinline__ float silu_f(float v) {
    return v * (1.0f / (1.0f + __expf(-v)));
}
__device__ __forceinline__ float softplus_f(float v) {
    return (v > 15.0f) ? v : log1pf(__expf(v));
}
__device__ __forceinline__ unsigned short f2bf(float f) {
    unsigned b = __float_as_uint(f);
    return (unsigned short)((b + 0x7FFFu + ((b >> 16) & 1u)) >> 16);
}
__device__ __forceinline__ float bf2f(unsigned short u) {
    return __uint_as_float((unsigned)u << 16);
}

#define GLOAD_LDS(gp, lp) \
    __builtin_amdgcn_global_load_lds((const __attribute__((address_space(1))) void*)(gp), \
                                     (__attribute__((address_space(3))) void*)(lp), 16, 0, 0)

// ================= prep: weight transposes + RMSNorm =================
// Blocked transpose (R7-verified, best-measured prep): W[K][N] fp32 ->
// BTb[N/16][K/32][16][32] bf16 (the 1KB unit one gload_lds consumes).
// CTA tile 64n x 128k via LDS [64n][136k] ushort. Reads 256B coalesced rows;
// writes one linear 1KB block per wave-instr (4KB runs).
__device__ __forceinline__ void transpose_blocked(const float* __restrict__ W,
                                                  unsigned short* __restrict__ BTb,
                                                  int K, int N, int bx, int by,
                                                  unsigned short* Tb) {
    const int tid = threadIdx.x;
    const int n0 = bx * 64, k0 = by * 128;
    #pragma unroll
    for (int i = 0; i < 8; ++i) {
        const int r = i * 16 + (tid >> 4);      // k-row 0..127
        const int c = (tid & 15) * 4;           // n-col 0..60
        float4 v = *(const float4*)&W[(size_t)(k0 + r) * N + n0 + c];
        Tb[(c + 0) * 136 + r] = f2bf(v.x);
        Tb[(c + 1) * 136 + r] = f2bf(v.y);
        Tb[(c + 2) * 136 + r] = f2bf(v.z);
        Tb[(c + 3) * 136 + r] = f2bf(v.w);
    }
    __syncthreads();
    const int wave = tid >> 6, lane = tid & 63;
    const int kblocks = K >> 5;
    #pragma unroll
    for (int t = 0; t < 4; ++t) {
        const int ob = wave * 4 + t;            // 0..15
        const int nb = ob >> 2, kb = ob & 3;
        const int n = nb * 16 + (lane >> 2);    // local n 0..63
        const int k = kb * 32 + (lane & 3) * 8; // local k 0..127
        bf16x8 v = *(const bf16x8*)&Tb[n * 136 + k];
        const size_t blk = (size_t)(((n0 >> 4) + nb)) * kblocks + ((k0 >> 5) + kb);
        *(bf16x8*)&BTb[blk * 512 + (size_t)lane * 8] = v;
    }
}

// Row-major reg-transpose (W_dt -> BTdt for the k128 kernel). R2-verified.
__device__ __forceinline__ void transpose_fast(const float* __restrict__ W,
                                               unsigned short* __restrict__ BT,
                                               int K, int N, int bx, int by) {
    const int wave = threadIdx.x >> 6, lane = threadIdx.x & 63;
    const int lr = lane >> 3, lc = lane & 7;
    const int k0 = by * 128 + (wave >> 1) * 64 + lr * 8;
    const int n0 = bx * 128 + (wave & 1) * 64 + lc * 8;
    float v[8][8];
    #pragma unroll
    for (int j = 0; j < 8; ++j) {
        float4 a = *(const float4*)&W[(size_t)(k0 + j) * N + n0];
        float4 b = *(const float4*)&W[(size_t)(k0 + j) * N + n0 + 4];
        v[j][0] = a.x; v[j][1] = a.y; v[j][2] = a.z; v[j][3] = a.w;
        v[j][4] = b.x; v[j][5] = b.y; v[j][6] = b.z; v[j][7] = b.w;
    }
    #pragma unroll
    for (int i = 0; i < 8; ++i) {
        bf16x8 o;
        #pragma unroll
        for (int j = 0; j < 8; ++j) o[j] = (short)f2bf(v[j][i]);
        *(bf16x8*)&BT[(size_t)(n0 + i) * K + k0] = o;
    }
}

// Legacy LDS path (only W_xp: N=160; 2.5 MB, conflicts negligible)
__device__ __forceinline__ void transpose_body(const float* __restrict__ W,
                                               unsigned short* __restrict__ BT,
                                               int K, int N, int bx, int by,
                                               unsigned short (*Tl)[72]) {
    const int k0 = by * 64, n0 = bx * 32;
    const int kr = threadIdx.x >> 3;
    const int nc = (threadIdx.x & 7) * 4;
    float4 v0 = *(const float4*)&W[(size_t)(k0 + kr) * N + n0 + nc];
    float4 v1 = *(const float4*)&W[(size_t)(k0 + kr + 32) * N + n0 + nc];
    Tl[nc + 0][kr] = f2bf(v0.x); Tl[nc + 1][kr] = f2bf(v0.y);
    Tl[nc + 2][kr] = f2bf(v0.z); Tl[nc + 3][kr] = f2bf(v0.w);
    Tl[nc + 0][kr + 32] = f2bf(v1.x); Tl[nc + 1][kr + 32] = f2bf(v1.y);
    Tl[nc + 2][kr + 32] = f2bf(v1.z); Tl[nc + 3][kr + 32] = f2bf(v1.w);
    __syncthreads();
    const int n = threadIdx.x >> 3;
    const int k8 = (threadIdx.x & 7) * 8;
    *(bf16x8*)&BT[(size_t)(n0 + n) * K + k0 + k8] = *(const bf16x8*)&Tl[n][k8];
}

// prep_win: W_in transpose only (2048 blocks) — split out for top-5 attribution.
__global__ __launch_bounds__(256) void prep_win_kernel(const float* __restrict__ W_in,
                                                       unsigned short* __restrict__ BT_in) {
    __shared__ __align__(16) unsigned short Tb[64 * 136];
    transpose_blocked(W_in, BT_in, DMODEL, N_XZ, blockIdx.x & 127, blockIdx.x >> 7, Tb);
}

// prep_rest: W_out blocked + W_dt fast + W_xp legacy + RMSNorm (2400 blocks).
__global__ __launch_bounds__(256) void prep_rest_kernel(const float* __restrict__ W_xp,
                                                        const float* __restrict__ W_dt,
                                                        const float* __restrict__ W_out,
                                                        const float* __restrict__ x,
                                                        const float* __restrict__ wn,
                                                        unsigned short* __restrict__ BTxp,
                                                        unsigned short* __restrict__ BTdt,
                                                        unsigned short* __restrict__ BT_out,
                                                        unsigned short* __restrict__ xn_bf) {
    __shared__ __align__(16) unsigned short Tb[64 * 136];
    __shared__ unsigned short Tl[32][72];
    __shared__ float red[4];
    int b = blockIdx.x;
    if (b < 1024) {                       // W_out blocked: 32 n-tiles x 32 k-tiles
        transpose_blocked(W_out, BT_out, DINNER, DMODEL, b & 31, b >> 5, Tb);
    } else if (b < 1056) {                // W_dt row-major: K=128, N=4096 (32 tiles)
        b -= 1024;
        transpose_fast(W_dt, BTdt, DTRANK, DINNER, b, 0);
    } else if (b < 1376) {                // W_xp legacy: K=4096, N=160
        b -= 1056;
        transpose_body(W_xp, BTxp, DINNER, N_XP, b % 5, b / 5, Tl);
    } else {                              // RMSNorm rows 0..1023
        const int row = b - 1376;
        const float4* xr = (const float4*)(x + (size_t)row * DMODEL);
        float ss = 0.f;
        float4 v0 = xr[threadIdx.x];
        float4 v1 = xr[threadIdx.x + 256];
        ss += v0.x*v0.x + v0.y*v0.y + v0.z*v0.z + v0.w*v0.w;
        ss += v1.x*v1.x + v1.y*v1.y + v1.z*v1.z + v1.w*v1.w;
        #pragma unroll
        for (int o = 32; o > 0; o >>= 1) ss += __shfl_down(ss, o);
        const int lane = threadIdx.x & 63, wv = threadIdx.x >> 6;
        if (lane == 0) red[wv] = ss;
        __syncthreads();
        if (threadIdx.x == 0) {
            float t = red[0] + red[1] + red[2] + red[3];
            red[0] = rsqrtf(t / (float)DMODEL + EPS_F);
        }
        __syncthreads();
        const float scale = red[0];
        const float4* wr = (const float4*)wn;
        float4 w0 = wr[threadIdx.x];
        float4 w1 = wr[threadIdx.x + 256];
        ushort4 o0, o1;
        o0.x = f2bf(v0.x * scale * w0.x); o0.y = f2bf(v0.y * scale * w0.y);
        o0.z = f2bf(v0.z * scale * w0.z); o0.w = f2bf(v0.w * scale * w0.w);
        o1.x = f2bf(v1.x * scale * w1.x); o1.y = f2bf(v1.y * scale * w1.y);
        o1.z = f2bf(v1.z * scale * w1.z); o1.w = f2bf(v1.w * scale * w1.w);
        unsigned short* outr = xn_bf + (size_t)row * DMODEL;
        *(ushort4*)&outr[threadIdx.x * 4] = o0;
        *(ushort4*)&outr[1024 + threadIdx.x * 4] = o1;
    }
}

// ================= bf16 MFMA GEMM, BK = KC*32 per barrier pair =================
// C(MxN) = A(MxK bf16) @ B^T. A row-major [M][K]. B operand: BLK=0 row-major BT[N][K];
// BLK=1 blocked BT[N/16][K/32][16][32] (1KB-contiguous gload_lds units).
// OUTM 0: bf16 plain   OUTM 2: fp32 split-K partial
template <int BM, int BN, int KC, int OUTM, int BLK>
__global__ __launch_bounds__(256) void gemm_mfma_kernel(const unsigned short* __restrict__ A,
                                                        const unsigned short* __restrict__ BT,
                                                        void* __restrict__ Cv,
                                                        int K, int Kc, int ldc, int Ncols,
                                                        const float* __restrict__ aux) {
    constexpr int MT = BM / 32;
    constexpr int NT = BN / 32;
    __shared__ __align__(16) unsigned short Al[KC * BM * 32];
    __shared__ __align__(16) unsigned short Bl[KC * BN * 32];
    const int tid = threadIdx.x;
    const int lane = tid & 63, wave = tid >> 6;
    const int wm = wave >> 1, wn = wave & 1;
    const int bm = blockIdx.y * BM, bn = blockIdx.x * BN;
    const size_t koff = (size_t)blockIdx.z * Kc;
    float* Cf = (float*)Cv;
    if (OUTM == 2) Cf += (size_t)blockIdx.z * (size_t)gridDim.y * BM * ldc;
    const int sr = lane >> 2;
    const int sk = (((lane & 3) ^ ((sr >> 1) & 3))) * 8;
    const int fr = lane & 15;
    const int fq = lane >> 4;
    const int fsw = (fq ^ ((fr >> 1) & 3)) * 8;

    f32x4 acc[MT][NT];
    #pragma unroll
    for (int i = 0; i < MT; ++i)
        #pragma unroll
        for (int j = 0; j < NT; ++j)
            acc[i][j] = (f32x4){0.f, 0.f, 0.f, 0.f};

    for (int k0 = 0; k0 < Kc; k0 += 32 * KC) {
        #pragma unroll
        for (int p = 0; p < KC; ++p) {
            #pragma unroll
            for (int is = wave; is < BM / 16; is += 4)
                GLOAD_LDS(&A[(size_t)(bm + is * 16 + sr) * K + koff + k0 + p * 32 + sk],
                          &Al[p * BM * 32 + is * 512]);
            #pragma unroll
            for (int is = wave; is < BN / 16; is += 4) {
                if (BLK) {
                    const size_t blk = (size_t)((bn >> 4) + is) * (K >> 5)
                                     + ((koff + k0 + p * 32) >> 5);
                    GLOAD_LDS(&BT[blk * 512 + sr * 32 + sk],
                              &Bl[p * BN * 32 + is * 512]);
                } else {
                    GLOAD_LDS(&BT[(size_t)(bn + is * 16 + sr) * K + koff + k0 + p * 32 + sk],
                              &Bl[p * BN * 32 + is * 512]);
                }
            }
        }
        __syncthreads();
        #pragma unroll
        for (int p = 0; p < KC; ++p) {
            bf16x8 af[MT], bfr[NT];
            #pragma unroll
            for (int i = 0; i < MT; ++i)
                af[i] = *(const bf16x8*)&Al[p * BM * 32 + (wm * (BM / 2) + i * 16 + fr) * 32 + fsw];
            #pragma unroll
            for (int j = 0; j < NT; ++j)
                bfr[j] = *(const bf16x8*)&Bl[p * BN * 32 + (wn * (BN / 2) + j * 16 + fr) * 32 + fsw];
            #pragma unroll
            for (int i = 0; i < MT; ++i)
                #pragma unroll
                for (int j = 0; j < NT; ++j)
                    acc[i][j] = __builtin_amdgcn_mfma_f32_16x16x32_bf16(af[i], bfr[j], acc[i][j], 0, 0, 0);
        }
        __syncthreads();
    }

    #pragma unroll
    for (int i = 0; i < MT; ++i) {
        const int row = bm + wm * (BM / 2) + i * 16 + fq * 4;
        #pragma unroll
        for (int j = 0; j < NT; ++j) {
            const int col = bn + wn * (BN / 2) + j * 16 + fr;
            if (col < Ncols) {
                #pragma unroll
                for (int r = 0; r < 4; ++r) {
                    float v = acc[i][j][r];
                    if (OUTM == 0) {
                        ((unsigned short*)Cv)[(size_t)(row + r) * ldc + col] = f2bf(v);
                    } else {
                        Cf[(size_t)(row + r) * ldc + col] = v;
                    }
                }
            }
        }
    }
}

// ============ K=128 GEMM, zero LDS: MFMA fragments loaded straight from L2/L3 ============
__global__ __launch_bounds__(256) void gemm_k128_softplus_kernel(
        const unsigned short* __restrict__ A,
        const unsigned short* __restrict__ BT,
        unsigned short* __restrict__ C,
        const float* __restrict__ bias) {
    const int lane = threadIdx.x & 63, wave = threadIdx.x >> 6;
    const int wm = wave >> 1, wn = wave & 1;
    const int fr = lane & 15, fq = lane >> 4;
    const int bm = blockIdx.y * 64, bn = blockIdx.x * 64;

    bf16x8 af[2][4], bfr[2][4];
    #pragma unroll
    for (int i = 0; i < 2; ++i) {
        const unsigned short* Ap = &A[(size_t)(bm + wm * 32 + i * 16 + fr) * DTRANK + fq * 8];
        #pragma unroll
        for (int kc = 0; kc < 4; ++kc) af[i][kc] = *(const bf16x8*)&Ap[kc * 32];
    }
    #pragma unroll
    for (int j = 0; j < 2; ++j) {
        const unsigned short* Bp = &BT[(size_t)(bn + wn * 32 + j * 16 + fr) * DTRANK + fq * 8];
        #pragma unroll
        for (int kc = 0; kc < 4; ++kc) bfr[j][kc] = *(const bf16x8*)&Bp[kc * 32];
    }

    f32x4 acc[2][2];
    #pragma unroll
    for (int i = 0; i < 2; ++i)
        #pragma unroll
        for (int j = 0; j < 2; ++j)
            acc[i][j] = (f32x4){0.f, 0.f, 0.f, 0.f};
    #pragma unroll
    for (int kc = 0; kc < 4; ++kc)
        #pragma unroll
        for (int i = 0; i < 2; ++i)
            #pragma unroll
            for (int j = 0; j < 2; ++j)
                acc[i][j] = __builtin_amdgcn_mfma_f32_16x16x32_bf16(af[i][kc], bfr[j][kc], acc[i][j], 0, 0, 0);

    #pragma unroll
    for (int i = 0; i < 2; ++i) {
        const int row = bm + wm * 32 + i * 16 + fq * 4;
        #pragma unroll
        for (int j = 0; j < 2; ++j) {
            const int col = bn + wn * 32 + j * 16 + fr;
            const float bc = bias[col];
            #pragma unroll
            for (int r = 0; r < 4; ++r)
                C[(size_t)(row + r) * DINNER + col] = f2bf(softplus_f(acc[i][j][r] + bc));
        }
    }
}

// ================= Depthwise causal conv (k=4) + SiLU, bf16 in/out, 8 ch/thread ==========
__global__ __launch_bounds__(256) void conv_silu_kernel(const unsigned short* __restrict__ xz_bf,
                                                        const float* __restrict__ cw,
                                                        const float* __restrict__ cb,
                                                        unsigned short* __restrict__ xs_bf) {
    const int idx = blockIdx.x * 256 + threadIdx.x;   // over L_SEQ * (DINNER/8)
    const int t = idx >> 9;
    const int c8 = (idx & 511) * 8;
    float acc[8];
    {
        float4 b0 = *(const float4*)&cb[c8];
        float4 b1 = *(const float4*)&cb[c8 + 4];
        acc[0] = b0.x; acc[1] = b0.y; acc[2] = b0.z; acc[3] = b0.w;
        acc[4] = b1.x; acc[5] = b1.y; acc[6] = b1.z; acc[7] = b1.w;
    }
    #pragma unroll
    for (int k = 0; k < 4; ++k) {
        const int tt = t + k - 3;
        if (tt >= 0) {
            bf16x8 xv = *(const bf16x8*)&xz_bf[(size_t)tt * N_XZ + c8];
            float4 w0 = *(const float4*)&cw[k * DINNER + c8];
            float4 w1 = *(const float4*)&cw[k * DINNER + c8 + 4];
            acc[0] = fmaf(bf2f((unsigned short)xv[0]), w0.x, acc[0]);
            acc[1] = fmaf(bf2f((unsigned short)xv[1]), w0.y, acc[1]);
            acc[2] = fmaf(bf2f((unsigned short)xv[2]), w0.z, acc[2]);
            acc[3] = fmaf(bf2f((unsigned short)xv[3]), w0.w, acc[3]);
            acc[4] = fmaf(bf2f((unsigned short)xv[4]), w1.x, acc[4]);
            acc[5] = fmaf(bf2f((unsigned short)xv[5]), w1.y, acc[5]);
            acc[6] = fmaf(bf2f((unsigned short)xv[6]), w1.z, acc[6]);
            acc[7] = fmaf(bf2f((unsigned short)xv[7]), w1.w, acc[7]);
        }
    }
    bf16x8 o;
    #pragma unroll
    for (int q = 0; q < 8; ++q) o[q] = (short)f2bf(silu_f(acc[q]));
    *(bf16x8*)&xs_bf[(size_t)t * DINNER + c8] = o;
}

// ================= reduce SK_XP split-K partials -> xdbc fp32 (+ bf16 dt cols) =================
__global__ __launch_bounds__(256) void reduce_sk_kernel(const float* __restrict__ part,
                                                        float* __restrict__ xdbc,
                                                        unsigned short* __restrict__ xdbc_dt) {
    const int i = (blockIdx.x * 256 + threadIdx.x) * 4;   // row*160 + col, 4-wide
    float4 s = make_float4(0.f, 0.f, 0.f, 0.f);
    #pragma unroll
    for (int c = 0; c < SK_XP; ++c) {
        float4 v = *(const float4*)&part[(size_t)c * (L_SEQ * N_XP) + i];
        s.x += v.x; s.y += v.y; s.z += v.z; s.w += v.w;
    }
    *(float4*)&xdbc[i] = s;
    const int col = i % N_XP;                              // multiple of 4; quad stays in-row
    if (col < DTRANK) {
        ushort4 o;
        o.x = f2bf(s.x); o.y = f2bf(s.y); o.z = f2bf(s.z); o.w = f2bf(s.w);
        *(ushort4*)&xdbc_dt[(i / N_XP) * DTRANK + col] = o;
    }
}

// ============ reduce 2 split-K partials + residual x -> out fp32 (step 7 tail) ============
__global__ __launch_bounds__(256) void reduce2_res_kernel(const float* __restrict__ part,
                                                          const float* __restrict__ x,
                                                          float* __restrict__ out) {
    const size_t i = ((size_t)blockIdx.x * 256 + threadIdx.x) * 4;
    float4 a = *(const float4*)&part[i];
    float4 b = *(const float4*)&part[(size_t)L_SEQ * DMODEL + i];
    float4 r = *(const float4*)&x[i];
    float4 o;
    o.x = a.x + b.x + r.x;
    o.y = a.y + b.y + r.y;
    o.z = a.z + b.z + r.z;
    o.w = a.w + b.w + r.w;
    *(float4*)&out[i] = o;
}

// ================= Selective scan, 3-pass chunked linear recurrence (bf16 inputs) ========
__global__ __launch_bounds__(256) void scan_pass1(const unsigned short* __restrict__ delta_bf,
                                                  const unsigned short* __restrict__ xs_bf,
                                                  const float* __restrict__ xdbc,
                                                  const float* __restrict__ A_log,
                                                  float* __restrict__ S,
                                                  float* __restrict__ sumdl) {
    __shared__ float BC[TCH][32];
    const int c = blockIdx.y;
    const int d = blockIdx.x * 256 + threadIdx.x;
    const int t0 = c * TCH;
    {
        const int tt = threadIdx.x >> 3, q = threadIdx.x & 7;
        *(float4*)&BC[tt][q * 4] =
            *(const float4*)&xdbc[(size_t)(t0 + tt) * N_XP + DTRANK + q * 4];
    }
    __syncthreads();
    float Aa[16];
    #pragma unroll
    for (int n = 0; n < 16; ++n) Aa[n] = -__expf(A_log[d * 16 + n]);
    float h[16];
    #pragma unroll
    for (int n = 0; n < 16; ++n) h[n] = 0.f;
    float sd = 0.f;
    for (int t = 0; t < TCH; ++t) {
        const float dl = bf2f(delta_bf[(size_t)(t0 + t) * DINNER + d]);
        const float u  = bf2f(xs_bf[(size_t)(t0 + t) * DINNER + d]);
        sd += dl;
        const float du = dl * u;
        #pragma unroll
        for (int n = 0; n < 16; ++n)
            h[n] = fmaf(h[n], __expf(dl * Aa[n]), du * BC[t][n]);
    }
    float* Sp = &S[((size_t)c * DINNER + d) * 16];
    #pragma unroll
    for (int n = 0; n < 16; n += 4)
        *(float4*)&Sp[n] = make_float4(h[n], h[n + 1], h[n + 2], h[n + 3]);
    sumdl[c * DINNER + d] = sd;
}

__global__ __launch_bounds__(256) void scan_pass2(const float* __restrict__ S,
                                                  const float* __restrict__ sumdl,
                                                  const float* __restrict__ A_log,
                                                  float* __restrict__ h0) {
    const int i = blockIdx.x * 256 + threadIdx.x;   // d*16 + n
    const int dd = i >> 4;
    const float A = -__expf(A_log[i]);
    float h = 0.f;
    #pragma unroll
    for (int c = 0; c < NCHUNK; ++c) {
        h0[(size_t)c * (DINNER * 16) + i] = h;
        h = h * __expf(A * sumdl[c * DINNER + dd]) + S[(size_t)c * (DINNER * 16) + i];
    }
}

__global__ __launch_bounds__(256) void scan_pass3(const unsigned short* __restrict__ delta_bf,
                                                  const unsigned short* __restrict__ xs_bf,
                                                  const float* __restrict__ xdbc,
                                                  const unsigned short* __restrict__ xz_bf,
                                                  const float* __restrict__ A_log,
                                                  const float* __restrict__ Dp,
                                                  const float* __restrict__ h0,
                                                  unsigned short* __restrict__ yg_bf) {
    __shared__ float BC[TCH][32];
    const int c = blockIdx.y;
    const int d = blockIdx.x * 256 + threadIdx.x;
    const int t0 = c * TCH;
    {
        const int tt = threadIdx.x >> 3, q = threadIdx.x & 7;
        *(float4*)&BC[tt][q * 4] =
            *(const float4*)&xdbc[(size_t)(t0 + tt) * N_XP + DTRANK + q * 4];
    }
    __syncthreads();
    float Aa[16];
    #pragma unroll
    for (int n = 0; n < 16; ++n) Aa[n] = -__expf(A_log[d * 16 + n]);
    float h[16];
    const float* h0p = &h0[(size_t)c * (DINNER * 16) + d * 16];
    #pragma unroll
    for (int n = 0; n < 16; n += 4) {
        float4 v = *(const float4*)&h0p[n];
        h[n] = v.x; h[n + 1] = v.y; h[n + 2] = v.z; h[n + 3] = v.w;
    }
    const float Dd = Dp[d];
    for (int t = 0; t < TCH; ++t) {
        const float dl = bf2f(delta_bf[(size_t)(t0 + t) * DINNER + d]);
        const float u  = bf2f(xs_bf[(size_t)(t0 + t) * DINNER + d]);
        const float du = dl * u;
        float y = 0.f;
        #pragma unroll
        for (int n = 0; n < 16; ++n) {
            h[n] = fmaf(h[n], __expf(dl * Aa[n]), du * BC[t][n]);
            y = fmaf(h[n], BC[t][16 + n], y);
        }
        const float res = bf2f(xz_bf[(size_t)(t0 + t) * N_XZ + DINNER + d]);
        yg_bf[(size_t)(t0 + t) * DINNER + d] = f2bf((y + u * Dd) * silu_f(res));
    }
}

extern "C" void kernel_launch(void* const* d_in, const int* in_sizes, int n_in,
                              void* d_out, int out_size, void* d_ws, size_t ws_size,
                              hipStream_t stream) {
    const float* x     = (const float*)d_in[0];
    const float* wn    = (const float*)d_in[1];
    const float* W_in  = (const float*)d_in[2];
    const float* cw    = (const float*)d_in[3];
    const float* cb    = (const float*)d_in[4];
    const float* W_xp  = (const float*)d_in[5];
    const float* W_dt  = (const float*)d_in[6];
    const float* b_dt  = (const float*)d_in[7];
    const float* A_log = (const float*)d_in[8];
    const float* Dp    = (const float*)d_in[9];
    const float* W_out = (const float*)d_in[10];
    float* out = (float*)d_out;

    float* ws = (float*)d_ws;                                     // offsets in floats
    unsigned short* xz_bf    = (unsigned short*)ws;               // [0, 4194304)
    unsigned short* xs_bf    = (unsigned short*)(ws + 4194304);   // [4194304, 6291456)
    unsigned short* yg_bf    = (unsigned short*)(ws + 6291456);   // [6291456, 8388608)
    unsigned short* delta_bf = (unsigned short*)(ws + 8388608);   // [8388608, 10485760)
    float*          part     = ws + 10485760;                     // step4: 2,621,440 f; step7 reuse: 4,194,304 f (spills into dead S)
    float*          S        = ws + 13107200;                     // 2,097,152 f
    float*          sumdl    = ws + 15204352;                     //   131,072 f
    float*          h0       = ws + 15335424;                     // 2,097,152 f
    float*          xdbc     = ws + 17432576;                     //   163,840 f
    unsigned short* xn_bf    = (unsigned short*)(ws + 17596416);  // 2,097,152 sh
    unsigned short* BTxp     = (unsigned short*)(ws + 18644992);  //   655,360 sh
    unsigned short* BTdt     = (unsigned short*)(ws + 18972672);  //   524,288 sh
    unsigned short* xdbc_dt  = (unsigned short*)(ws + 19234816);  //   131,072 sh
    unsigned short* BT_in    = (unsigned short*)(ws + 19300352);  // 16,777,216 sh (blocked)
    unsigned short* BT_out   = (unsigned short*)(ws + 27688960);  //  8,388,608 sh (blocked)
    // total: 31,883,264 f = 127.5 MB

    // 1a. W_in blocked transpose (split out for top-5 attribution)
    prep_win_kernel<<<2048, 256, 0, stream>>>(W_in, BT_in);
    // 1b. W_out blocked + W_dt + W_xp + RMSNorm
    prep_rest_kernel<<<2400, 256, 0, stream>>>(W_xp, W_dt, W_out, x, wn,
                                               BTxp, BTdt, BT_out, xn_bf);
    // 2. xz = xn @ W_in -> bf16  (128x128, blocked-B: 1KB-linear gload_lds)
    gemm_mfma_kernel<128, 128, 2, 0, 1><<<dim3(N_XZ / 128, L_SEQ / 128), 256, 0, stream>>>(
        xn_bf, BT_in, xz_bf, DMODEL, DMODEL, N_XZ, N_XZ, nullptr);
    // 3. conv + silu -> xs bf16 (8 ch/thread, 16B vector loads)
    conv_silu_kernel<<<(L_SEQ * DINNER / 8) / 256, 256, 0, stream>>>(xz_bf, cw, cb, xs_bf);
    // 4. xdbc = xs @ W_xp  (split-K x16, fp32 partials, row-major B)
    gemm_mfma_kernel<64, 64, 2, 2, 0><<<dim3(3, L_SEQ / 64, SK_XP), 256, 0, stream>>>(
        xs_bf, BTxp, part, DINNER, DINNER / SK_XP, N_XP, N_XP, nullptr);
    reduce_sk_kernel<<<(L_SEQ * N_XP / 4) / 256, 256, 0, stream>>>(part, xdbc, xdbc_dt);
    // 5. delta = softplus(xdbc_dt @ W_dt + b_dt) -> bf16  (zero-LDS direct-reg K=128 GEMM)
    gemm_k128_softplus_kernel<<<dim3(DINNER / 64, L_SEQ / 64), 256, 0, stream>>>(
        xdbc_dt, BTdt, delta_bf, b_dt);
    // 6. selective scan (3 passes, 32 chunks) + gate -> yg bf16
    scan_pass1<<<dim3(DINNER / 256, NCHUNK), 256, 0, stream>>>(delta_bf, xs_bf, xdbc, A_log, S, sumdl);
    scan_pass2<<<(DINNER * 16) / 256, 256, 0, stream>>>(S, sumdl, A_log, h0);
    scan_pass3<<<dim3(DINNER / 256, NCHUNK), 256, 0, stream>>>(delta_bf, xs_bf, xdbc, xz_bf,
                                                               A_log, Dp, h0, yg_bf);
    // 7. out = yg @ W_out (64x128, blocked-B, split-K x2 -> 512 blocks = 2/CU, fp32 partials)
    gemm_mfma_kernel<64, 128, 2, 2, 1><<<dim3(DMODEL / 128, L_SEQ / 64, 2), 256, 0, stream>>>(
        yg_bf, BT_out, part, DINNER, DINNER / 2, DMODEL, DMODEL, nullptr);
    //    reduce partials + residual x -> out
    reduce2_res_kernel<<<(L_SEQ * DMODEL) / 1024, 256, 0, stream>>>(part, x, out);
}

// Round 11
// 323.306 us; speedup vs baseline: 1.0889x; 1.0248x over previous
//
#include <hip/hip_runtime.h>
#include <math.h>

#define L_SEQ   1024
#define DMODEL  2048
#define DINNER  4096
#define DSTATE  16
#define DTRANK  128
#define N_XZ    (2 * DINNER)            // 8192
#define N_XP    (DTRANK + 2 * DSTATE)   // 160
#define EPS_F   1e-5f
#define NCHUNK  32
#define TCH     32
#define SK_XP   16                      // split-K for xdbc GEMM

using bf16x8 = __attribute__((ext_vector_type(8))) short;
using f32x4  = __attribute__((ext_vector_type(4))) float;

__device__ __forceinline__ float silu_f(float v) {
    return v * (1.0f / (1.0f + __expf(-v)));
}
__device__ __forceinline__ float softplus_f(float v) {
    return (v > 15.0f) ? v : log1pf(__expf(v));
}
__device__ __forceinline__ unsigned short f2bf(float f) {
    unsigned b = __float_as_uint(f);
    return (unsigned short)((b + 0x7FFFu + ((b >> 16) & 1u)) >> 16);
}
__device__ __forceinline__ float bf2f(unsigned short u) {
    return __uint_as_float((unsigned)u << 16);
}

#define GLOAD_LDS(gp, lp) \
    __builtin_amdgcn_global_load_lds((const __attribute__((address_space(1))) void*)(gp), \
                                     (__attribute__((address_space(3))) void*)(lp), 16, 0, 0)

// ================= prep: weight transposes + RMSNorm =================
// Blocked transpose (R7/R9-verified): W[K][N] fp32 -> BTb[N/16][K/32][16][32] bf16
// (the 1KB unit one gload_lds consumes). CTA tile 64n x 128k via LDS [64n][136k].
__device__ __forceinline__ void transpose_blocked(const float* __restrict__ W,
                                                  unsigned short* __restrict__ BTb,
                                                  int K, int N, int bx, int by,
                                                  unsigned short* Tb) {
    const int tid = threadIdx.x;
    const int n0 = bx * 64, k0 = by * 128;
    #pragma unroll
    for (int i = 0; i < 8; ++i) {
        const int r = i * 16 + (tid >> 4);      // k-row 0..127
        const int c = (tid & 15) * 4;           // n-col 0..60
        float4 v = *(const float4*)&W[(size_t)(k0 + r) * N + n0 + c];
        Tb[(c + 0) * 136 + r] = f2bf(v.x);
        Tb[(c + 1) * 136 + r] = f2bf(v.y);
        Tb[(c + 2) * 136 + r] = f2bf(v.z);
        Tb[(c + 3) * 136 + r] = f2bf(v.w);
    }
    __syncthreads();
    const int wave = tid >> 6, lane = tid & 63;
    const int kblocks = K >> 5;
    #pragma unroll
    for (int t = 0; t < 4; ++t) {
        const int ob = wave * 4 + t;            // 0..15
        const int nb = ob >> 2, kb = ob & 3;
        const int n = nb * 16 + (lane >> 2);    // local n 0..63
        const int k = kb * 32 + (lane & 3) * 8; // local k 0..127
        bf16x8 v = *(const bf16x8*)&Tb[n * 136 + k];
        const size_t blk = (size_t)(((n0 >> 4) + nb)) * kblocks + ((k0 >> 5) + kb);
        *(bf16x8*)&BTb[blk * 512 + (size_t)lane * 8] = v;
    }
}

// Row-major reg-transpose (W_dt -> BTdt for the k128 kernel). R2-verified.
__device__ __forceinline__ void transpose_fast(const float* __restrict__ W,
                                               unsigned short* __restrict__ BT,
                                               int K, int N, int bx, int by) {
    const int wave = threadIdx.x >> 6, lane = threadIdx.x & 63;
    const int lr = lane >> 3, lc = lane & 7;
    const int k0 = by * 128 + (wave >> 1) * 64 + lr * 8;
    const int n0 = bx * 128 + (wave & 1) * 64 + lc * 8;
    float v[8][8];
    #pragma unroll
    for (int j = 0; j < 8; ++j) {
        float4 a = *(const float4*)&W[(size_t)(k0 + j) * N + n0];
        float4 b = *(const float4*)&W[(size_t)(k0 + j) * N + n0 + 4];
        v[j][0] = a.x; v[j][1] = a.y; v[j][2] = a.z; v[j][3] = a.w;
        v[j][4] = b.x; v[j][5] = b.y; v[j][6] = b.z; v[j][7] = b.w;
    }
    #pragma unroll
    for (int i = 0; i < 8; ++i) {
        bf16x8 o;
        #pragma unroll
        for (int j = 0; j < 8; ++j) o[j] = (short)f2bf(v[j][i]);
        *(bf16x8*)&BT[(size_t)(n0 + i) * K + k0] = o;
    }
}

// Legacy LDS path (only W_xp: N=160; 2.5 MB, conflicts negligible)
__device__ __forceinline__ void transpose_body(const float* __restrict__ W,
                                               unsigned short* __restrict__ BT,
                                               int K, int N, int bx, int by,
                                               unsigned short (*Tl)[72]) {
    const int k0 = by * 64, n0 = bx * 32;
    const int kr = threadIdx.x >> 3;
    const int nc = (threadIdx.x & 7) * 4;
    float4 v0 = *(const float4*)&W[(size_t)(k0 + kr) * N + n0 + nc];
    float4 v1 = *(const float4*)&W[(size_t)(k0 + kr + 32) * N + n0 + nc];
    Tl[nc + 0][kr] = f2bf(v0.x); Tl[nc + 1][kr] = f2bf(v0.y);
    Tl[nc + 2][kr] = f2bf(v0.z); Tl[nc + 3][kr] = f2bf(v0.w);
    Tl[nc + 0][kr + 32] = f2bf(v1.x); Tl[nc + 1][kr + 32] = f2bf(v1.y);
    Tl[nc + 2][kr + 32] = f2bf(v1.z); Tl[nc + 3][kr + 32] = f2bf(v1.w);
    __syncthreads();
    const int n = threadIdx.x >> 3;
    const int k8 = (threadIdx.x & 7) * 8;
    *(bf16x8*)&BT[(size_t)(n0 + n) * K + k0 + k8] = *(const bf16x8*)&Tl[n][k8];
}

// prep_win: W_in transpose only (2048 blocks) — split out for top-5 attribution.
__global__ __launch_bounds__(256) void prep_win_kernel(const float* __restrict__ W_in,
                                                       unsigned short* __restrict__ BT_in) {
    __shared__ __align__(16) unsigned short Tb[64 * 136];
    transpose_blocked(W_in, BT_in, DMODEL, N_XZ, blockIdx.x & 127, blockIdx.x >> 7, Tb);
}

// prep_rest: W_out blocked + W_dt fast + W_xp legacy + RMSNorm (2400 blocks).
__global__ __launch_bounds__(256) void prep_rest_kernel(const float* __restrict__ W_xp,
                                                        const float* __restrict__ W_dt,
                                                        const float* __restrict__ W_out,
                                                        const float* __restrict__ x,
                                                        const float* __restrict__ wn,
                                                        unsigned short* __restrict__ BTxp,
                                                        unsigned short* __restrict__ BTdt,
                                                        unsigned short* __restrict__ BT_out,
                                                        unsigned short* __restrict__ xn_bf) {
    __shared__ __align__(16) unsigned short Tb[64 * 136];
    __shared__ unsigned short Tl[32][72];
    __shared__ float red[4];
    int b = blockIdx.x;
    if (b < 1024) {                       // W_out blocked: 32 n-tiles x 32 k-tiles
        transpose_blocked(W_out, BT_out, DINNER, DMODEL, b & 31, b >> 5, Tb);
    } else if (b < 1056) {                // W_dt row-major: K=128, N=4096 (32 tiles)
        b -= 1024;
        transpose_fast(W_dt, BTdt, DTRANK, DINNER, b, 0);
    } else if (b < 1376) {                // W_xp legacy: K=4096, N=160
        b -= 1056;
        transpose_body(W_xp, BTxp, DINNER, N_XP, b % 5, b / 5, Tl);
    } else {                              // RMSNorm rows 0..1023
        const int row = b - 1376;
        const float4* xr = (const float4*)(x + (size_t)row * DMODEL);
        float ss = 0.f;
        float4 v0 = xr[threadIdx.x];
        float4 v1 = xr[threadIdx.x + 256];
        ss += v0.x*v0.x + v0.y*v0.y + v0.z*v0.z + v0.w*v0.w;
        ss += v1.x*v1.x + v1.y*v1.y + v1.z*v1.z + v1.w*v1.w;
        #pragma unroll
        for (int o = 32; o > 0; o >>= 1) ss += __shfl_down(ss, o);
        const int lane = threadIdx.x & 63, wv = threadIdx.x >> 6;
        if (lane == 0) red[wv] = ss;
        __syncthreads();
        if (threadIdx.x == 0) {
            float t = red[0] + red[1] + red[2] + red[3];
            red[0] = rsqrtf(t / (float)DMODEL + EPS_F);
        }
        __syncthreads();
        const float scale = red[0];
        const float4* wr = (const float4*)wn;
        float4 w0 = wr[threadIdx.x];
        float4 w1 = wr[threadIdx.x + 256];
        ushort4 o0, o1;
        o0.x = f2bf(v0.x * scale * w0.x); o0.y = f2bf(v0.y * scale * w0.y);
        o0.z = f2bf(v0.z * scale * w0.z); o0.w = f2bf(v0.w * scale * w0.w);
        o1.x = f2bf(v1.x * scale * w1.x); o1.y = f2bf(v1.y * scale * w1.y);
        o1.z = f2bf(v1.z * scale * w1.z); o1.w = f2bf(v1.w * scale * w1.w);
        unsigned short* outr = xn_bf + (size_t)row * DMODEL;
        *(ushort4*)&outr[threadIdx.x * 4] = o0;
        *(ushort4*)&outr[1024 + threadIdx.x * 4] = o1;
    }
}

// ================= bf16 MFMA GEMM, BK = KC*32 per barrier pair =================
// C(MxN) = A(MxK bf16) @ B^T. A row-major [M][K]. B operand: BLK=0 row-major BT[N][K];
// BLK=1 blocked BT[N/16][K/32][16][32] (1KB-contiguous gload_lds units).
// OUTM 0: bf16 plain   OUTM 2: fp32 split-K partial
template <int BM, int BN, int KC, int OUTM, int BLK>
__global__ __launch_bounds__(256) void gemm_mfma_kernel(const unsigned short* __restrict__ A,
                                                        const unsigned short* __restrict__ BT,
                                                        void* __restrict__ Cv,
                                                        int K, int Kc, int ldc, int Ncols,
                                                        const float* __restrict__ aux) {
    constexpr int MT = BM / 32;
    constexpr int NT = BN / 32;
    __shared__ __align__(16) unsigned short Al[KC * BM * 32];
    __shared__ __align__(16) unsigned short Bl[KC * BN * 32];
    const int tid = threadIdx.x;
    const int lane = tid & 63, wave = tid >> 6;
    const int wm = wave >> 1, wn = wave & 1;
    const int bm = blockIdx.y * BM, bn = blockIdx.x * BN;
    const size_t koff = (size_t)blockIdx.z * Kc;
    float* Cf = (float*)Cv;
    if (OUTM == 2) Cf += (size_t)blockIdx.z * (size_t)gridDim.y * BM * ldc;
    const int sr = lane >> 2;
    const int sk = (((lane & 3) ^ ((sr >> 1) & 3))) * 8;
    const int fr = lane & 15;
    const int fq = lane >> 4;
    const int fsw = (fq ^ ((fr >> 1) & 3)) * 8;

    f32x4 acc[MT][NT];
    #pragma unroll
    for (int i = 0; i < MT; ++i)
        #pragma unroll
        for (int j = 0; j < NT; ++j)
            acc[i][j] = (f32x4){0.f, 0.f, 0.f, 0.f};

    for (int k0 = 0; k0 < Kc; k0 += 32 * KC) {
        #pragma unroll
        for (int p = 0; p < KC; ++p) {
            #pragma unroll
            for (int is = wave; is < BM / 16; is += 4)
                GLOAD_LDS(&A[(size_t)(bm + is * 16 + sr) * K + koff + k0 + p * 32 + sk],
                          &Al[p * BM * 32 + is * 512]);
            #pragma unroll
            for (int is = wave; is < BN / 16; is += 4) {
                if (BLK) {
                    const size_t blk = (size_t)((bn >> 4) + is) * (K >> 5)
                                     + ((koff + k0 + p * 32) >> 5);
                    GLOAD_LDS(&BT[blk * 512 + sr * 32 + sk],
                              &Bl[p * BN * 32 + is * 512]);
                } else {
                    GLOAD_LDS(&BT[(size_t)(bn + is * 16 + sr) * K + koff + k0 + p * 32 + sk],
                              &Bl[p * BN * 32 + is * 512]);
                }
            }
        }
        __syncthreads();
        #pragma unroll
        for (int p = 0; p < KC; ++p) {
            bf16x8 af[MT], bfr[NT];
            #pragma unroll
            for (int i = 0; i < MT; ++i)
                af[i] = *(const bf16x8*)&Al[p * BM * 32 + (wm * (BM / 2) + i * 16 + fr) * 32 + fsw];
            #pragma unroll
            for (int j = 0; j < NT; ++j)
                bfr[j] = *(const bf16x8*)&Bl[p * BN * 32 + (wn * (BN / 2) + j * 16 + fr) * 32 + fsw];
            #pragma unroll
            for (int i = 0; i < MT; ++i)
                #pragma unroll
                for (int j = 0; j < NT; ++j)
                    acc[i][j] = __builtin_amdgcn_mfma_f32_16x16x32_bf16(af[i], bfr[j], acc[i][j], 0, 0, 0);
        }
        __syncthreads();
    }

    #pragma unroll
    for (int i = 0; i < MT; ++i) {
        const int row = bm + wm * (BM / 2) + i * 16 + fq * 4;
        #pragma unroll
        for (int j = 0; j < NT; ++j) {
            const int col = bn + wn * (BN / 2) + j * 16 + fr;
            if (col < Ncols) {
                #pragma unroll
                for (int r = 0; r < 4; ++r) {
                    float v = acc[i][j][r];
                    if (OUTM == 0) {
                        ((unsigned short*)Cv)[(size_t)(row + r) * ldc + col] = f2bf(v);
                    } else {
                        Cf[(size_t)(row + r) * ldc + col] = v;
                    }
                }
            }
        }
    }
}

// ============ K=128 GEMM, zero LDS: MFMA fragments loaded straight from L2/L3 ============
__global__ __launch_bounds__(256) void gemm_k128_softplus_kernel(
        const unsigned short* __restrict__ A,
        const unsigned short* __restrict__ BT,
        unsigned short* __restrict__ C,
        const float* __restrict__ bias) {
    const int lane = threadIdx.x & 63, wave = threadIdx.x >> 6;
    const int wm = wave >> 1, wn = wave & 1;
    const int fr = lane & 15, fq = lane >> 4;
    const int bm = blockIdx.y * 64, bn = blockIdx.x * 64;

    bf16x8 af[2][4], bfr[2][4];
    #pragma unroll
    for (int i = 0; i < 2; ++i) {
        const unsigned short* Ap = &A[(size_t)(bm + wm * 32 + i * 16 + fr) * DTRANK + fq * 8];
        #pragma unroll
        for (int kc = 0; kc < 4; ++kc) af[i][kc] = *(const bf16x8*)&Ap[kc * 32];
    }
    #pragma unroll
    for (int j = 0; j < 2; ++j) {
        const unsigned short* Bp = &BT[(size_t)(bn + wn * 32 + j * 16 + fr) * DTRANK + fq * 8];
        #pragma unroll
        for (int kc = 0; kc < 4; ++kc) bfr[j][kc] = *(const bf16x8*)&Bp[kc * 32];
    }

    f32x4 acc[2][2];
    #pragma unroll
    for (int i = 0; i < 2; ++i)
        #pragma unroll
        for (int j = 0; j < 2; ++j)
            acc[i][j] = (f32x4){0.f, 0.f, 0.f, 0.f};
    #pragma unroll
    for (int kc = 0; kc < 4; ++kc)
        #pragma unroll
        for (int i = 0; i < 2; ++i)
            #pragma unroll
            for (int j = 0; j < 2; ++j)
                acc[i][j] = __builtin_amdgcn_mfma_f32_16x16x32_bf16(af[i][kc], bfr[j][kc], acc[i][j], 0, 0, 0);

    #pragma unroll
    for (int i = 0; i < 2; ++i) {
        const int row = bm + wm * 32 + i * 16 + fq * 4;
        #pragma unroll
        for (int j = 0; j < 2; ++j) {
            const int col = bn + wn * 32 + j * 16 + fr;
            const float bc = bias[col];
            #pragma unroll
            for (int r = 0; r < 4; ++r)
                C[(size_t)(row + r) * DINNER + col] = f2bf(softplus_f(acc[i][j][r] + bc));
        }
    }
}

// ================= Depthwise causal conv (k=4) + SiLU, bf16 in/out, 8 ch/thread ==========
__global__ __launch_bounds__(256) void conv_silu_kernel(const unsigned short* __restrict__ xz_bf,
                                                        const float* __restrict__ cw,
                                                        const float* __restrict__ cb,
                                                        unsigned short* __restrict__ xs_bf) {
    const int idx = blockIdx.x * 256 + threadIdx.x;   // over L_SEQ * (DINNER/8)
    const int t = idx >> 9;
    const int c8 = (idx & 511) * 8;
    float acc[8];
    {
        float4 b0 = *(const float4*)&cb[c8];
        float4 b1 = *(const float4*)&cb[c8 + 4];
        acc[0] = b0.x; acc[1] = b0.y; acc[2] = b0.z; acc[3] = b0.w;
        acc[4] = b1.x; acc[5] = b1.y; acc[6] = b1.z; acc[7] = b1.w;
    }
    #pragma unroll
    for (int k = 0; k < 4; ++k) {
        const int tt = t + k - 3;
        if (tt >= 0) {
            bf16x8 xv = *(const bf16x8*)&xz_bf[(size_t)tt * N_XZ + c8];
            float4 w0 = *(const float4*)&cw[k * DINNER + c8];
            float4 w1 = *(const float4*)&cw[k * DINNER + c8 + 4];
            acc[0] = fmaf(bf2f((unsigned short)xv[0]), w0.x, acc[0]);
            acc[1] = fmaf(bf2f((unsigned short)xv[1]), w0.y, acc[1]);
            acc[2] = fmaf(bf2f((unsigned short)xv[2]), w0.z, acc[2]);
            acc[3] = fmaf(bf2f((unsigned short)xv[3]), w0.w, acc[3]);
            acc[4] = fmaf(bf2f((unsigned short)xv[4]), w1.x, acc[4]);
            acc[5] = fmaf(bf2f((unsigned short)xv[5]), w1.y, acc[5]);
            acc[6] = fmaf(bf2f((unsigned short)xv[6]), w1.z, acc[6]);
            acc[7] = fmaf(bf2f((unsigned short)xv[7]), w1.w, acc[7]);
        }
    }
    bf16x8 o;
    #pragma unroll
    for (int q = 0; q < 8; ++q) o[q] = (short)f2bf(silu_f(acc[q]));
    *(bf16x8*)&xs_bf[(size_t)t * DINNER + c8] = o;
}

// ================= reduce SK_XP split-K partials -> xdbc fp32 (+ bf16 dt cols) =================
__global__ __launch_bounds__(256) void reduce_sk_kernel(const float* __restrict__ part,
                                                        float* __restrict__ xdbc,
                                                        unsigned short* __restrict__ xdbc_dt) {
    const int i = (blockIdx.x * 256 + threadIdx.x) * 4;   // row*160 + col, 4-wide
    float4 s = make_float4(0.f, 0.f, 0.f, 0.f);
    #pragma unroll
    for (int c = 0; c < SK_XP; ++c) {
        float4 v = *(const float4*)&part[(size_t)c * (L_SEQ * N_XP) + i];
        s.x += v.x; s.y += v.y; s.z += v.z; s.w += v.w;
    }
    *(float4*)&xdbc[i] = s;
    const int col = i % N_XP;                              // multiple of 4; quad stays in-row
    if (col < DTRANK) {
        ushort4 o;
        o.x = f2bf(s.x); o.y = f2bf(s.y); o.z = f2bf(s.z); o.w = f2bf(s.w);
        *(ushort4*)&xdbc_dt[(i / N_XP) * DTRANK + col] = o;
    }
}

// ============ reduce 2 split-K partials + residual x -> out fp32 (step 7 tail) ============
__global__ __launch_bounds__(256) void reduce2_res_kernel(const float* __restrict__ part,
                                                          const float* __restrict__ x,
                                                          float* __restrict__ out) {
    const size_t i = ((size_t)blockIdx.x * 256 + threadIdx.x) * 4;
    float4 a = *(const float4*)&part[i];
    float4 b = *(const float4*)&part[(size_t)L_SEQ * DMODEL + i];
    float4 r = *(const float4*)&x[i];
    float4 o;
    o.x = a.x + b.x + r.x;
    o.y = a.y + b.y + r.y;
    o.z = a.z + b.z + r.z;
    o.w = a.w + b.w + r.w;
    *(float4*)&out[i] = o;
}

// ================= Selective scan, 3-pass chunked linear recurrence =================
// pass1/pass3: inputs staged tile-wise through LDS with bf16x8 loads (G13 —
// replaces 2B/lane scalar bf16 global loads; 8x fewer requests, issued up-front).
__global__ __launch_bounds__(256) void scan_pass1(const unsigned short* __restrict__ delta_bf,
                                                  const unsigned short* __restrict__ xs_bf,
                                                  const float* __restrict__ xdbc,
                                                  const float* __restrict__ A_log,
                                                  float* __restrict__ S,
                                                  float* __restrict__ sumdl) {
    __shared__ float BC[TCH][32];
    __shared__ __align__(16) unsigned short DL[TCH][256];
    __shared__ __align__(16) unsigned short US[TCH][256];
    const int c = blockIdx.y;
    const int tid = threadIdx.x;
    const int d0 = blockIdx.x * 256;
    const int d = d0 + tid;
    const int t0 = c * TCH;
    {
        const int tt = tid >> 3, q = tid & 7;
        *(float4*)&BC[tt][q * 4] =
            *(const float4*)&xdbc[(size_t)(t0 + tt) * N_XP + DTRANK + q * 4];
    }
    #pragma unroll
    for (int u = 0; u < 4; ++u) {
        const int l = tid + 256 * u;
        const int r = l >> 5, cc = (l & 31) * 8;
        *(bf16x8*)&DL[r][cc] = *(const bf16x8*)&delta_bf[(size_t)(t0 + r) * DINNER + d0 + cc];
        *(bf16x8*)&US[r][cc] = *(const bf16x8*)&xs_bf[(size_t)(t0 + r) * DINNER + d0 + cc];
    }
    __syncthreads();
    float Aa[16];
    #pragma unroll
    for (int n = 0; n < 16; n += 4) {
        float4 a = *(const float4*)&A_log[(size_t)d * 16 + n];
        Aa[n]     = -__expf(a.x); Aa[n + 1] = -__expf(a.y);
        Aa[n + 2] = -__expf(a.z); Aa[n + 3] = -__expf(a.w);
    }
    float h[16];
    #pragma unroll
    for (int n = 0; n < 16; ++n) h[n] = 0.f;
    float sd = 0.f;
    for (int t = 0; t < TCH; ++t) {
        const float dl = bf2f(DL[t][tid]);
        const float u  = bf2f(US[t][tid]);
        sd += dl;
        const float du = dl * u;
        #pragma unroll
        for (int n = 0; n < 16; ++n)
            h[n] = fmaf(h[n], __expf(dl * Aa[n]), du * BC[t][n]);
    }
    float* Sp = &S[((size_t)c * DINNER + d) * 16];
    #pragma unroll
    for (int n = 0; n < 16; n += 4)
        *(float4*)&Sp[n] = make_float4(h[n], h[n + 1], h[n + 2], h[n + 3]);
    sumdl[c * DINNER + d] = sd;
}

__global__ __launch_bounds__(256) void scan_pass2(const float* __restrict__ S,
                                                  const float* __restrict__ sumdl,
                                                  const float* __restrict__ A_log,
                                                  float* __restrict__ h0) {
    const int i = blockIdx.x * 256 + threadIdx.x;   // d*16 + n
    const int dd = i >> 4;
    const float A = -__expf(A_log[i]);
    float h = 0.f;
    #pragma unroll
    for (int c = 0; c < NCHUNK; ++c) {
        h0[(size_t)c * (DINNER * 16) + i] = h;
        h = h * __expf(A * sumdl[c * DINNER + dd]) + S[(size_t)c * (DINNER * 16) + i];
    }
}

__global__ __launch_bounds__(256) void scan_pass3(const unsigned short* __restrict__ delta_bf,
                                                  const unsigned short* __restrict__ xs_bf,
                                                  const float* __restrict__ xdbc,
                                                  const unsigned short* __restrict__ xz_bf,
                                                  const float* __restrict__ A_log,
                                                  const float* __restrict__ Dp,
                                                  const float* __restrict__ h0,
                                                  unsigned short* __restrict__ yg_bf) {
    __shared__ float BC[TCH][32];
    __shared__ __align__(16) unsigned short DL[TCH][256];
    __shared__ __align__(16) unsigned short US[TCH][256];
    __shared__ __align__(16) unsigned short RS[TCH][256];
    __shared__ __align__(16) unsigned short YG[TCH][256];
    const int c = blockIdx.y;
    const int tid = threadIdx.x;
    const int d0 = blockIdx.x * 256;
    const int d = d0 + tid;
    const int t0 = c * TCH;
    {
        const int tt = tid >> 3, q = tid & 7;
        *(float4*)&BC[tt][q * 4] =
            *(const float4*)&xdbc[(size_t)(t0 + tt) * N_XP + DTRANK + q * 4];
    }
    #pragma unroll
    for (int u = 0; u < 4; ++u) {
        const int l = tid + 256 * u;
        const int r = l >> 5, cc = (l & 31) * 8;
        *(bf16x8*)&DL[r][cc] = *(const bf16x8*)&delta_bf[(size_t)(t0 + r) * DINNER + d0 + cc];
        *(bf16x8*)&US[r][cc] = *(const bf16x8*)&xs_bf[(size_t)(t0 + r) * DINNER + d0 + cc];
        *(bf16x8*)&RS[r][cc] =
            *(const bf16x8*)&xz_bf[(size_t)(t0 + r) * N_XZ + DINNER + d0 + cc];
    }
    __syncthreads();
    float Aa[16];
    #pragma unroll
    for (int n = 0; n < 16; n += 4) {
        float4 a = *(const float4*)&A_log[(size_t)d * 16 + n];
        Aa[n]     = -__expf(a.x); Aa[n + 1] = -__expf(a.y);
        Aa[n + 2] = -__expf(a.z); Aa[n + 3] = -__expf(a.w);
    }
    float h[16];
    const float* h0p = &h0[(size_t)c * (DINNER * 16) + d * 16];
    #pragma unroll
    for (int n = 0; n < 16; n += 4) {
        float4 v = *(const float4*)&h0p[n];
        h[n] = v.x; h[n + 1] = v.y; h[n + 2] = v.z; h[n + 3] = v.w;
    }
    const float Dd = Dp[d];
    for (int t = 0; t < TCH; ++t) {
        const float dl = bf2f(DL[t][tid]);
        const float u  = bf2f(US[t][tid]);
        const float du = dl * u;
        float y = 0.f;
        #pragma unroll
        for (int n = 0; n < 16; ++n) {
            h[n] = fmaf(h[n], __expf(dl * Aa[n]), du * BC[t][n]);
            y = fmaf(h[n], BC[t][16 + n], y);
        }
        const float res = bf2f(RS[t][tid]);
        YG[t][tid] = f2bf((y + u * Dd) * silu_f(res));
    }
    __syncthreads();
    #pragma unroll
    for (int u = 0; u < 4; ++u) {
        const int l = tid + 256 * u;
        const int r = l >> 5, cc = (l & 31) * 8;
        *(bf16x8*)&yg_bf[(size_t)(t0 + r) * DINNER + d0 + cc] = *(const bf16x8*)&YG[r][cc];
    }
}

extern "C" void kernel_launch(void* const* d_in, const int* in_sizes, int n_in,
                              void* d_out, int out_size, void* d_ws, size_t ws_size,
                              hipStream_t stream) {
    const float* x     = (const float*)d_in[0];
    const float* wn    = (const float*)d_in[1];
    const float* W_in  = (const float*)d_in[2];
    const float* cw    = (const float*)d_in[3];
    const float* cb    = (const float*)d_in[4];
    const float* W_xp  = (const float*)d_in[5];
    const float* W_dt  = (const float*)d_in[6];
    const float* b_dt  = (const float*)d_in[7];
    const float* A_log = (const float*)d_in[8];
    const float* Dp    = (const float*)d_in[9];
    const float* W_out = (const float*)d_in[10];
    float* out = (float*)d_out;

    float* ws = (float*)d_ws;                                     // offsets in floats
    unsigned short* xz_bf    = (unsigned short*)ws;               // [0, 4194304)
    unsigned short* xs_bf    = (unsigned short*)(ws + 4194304);   // [4194304, 6291456)
    unsigned short* yg_bf    = (unsigned short*)(ws + 6291456);   // [6291456, 8388608)
    unsigned short* delta_bf = (unsigned short*)(ws + 8388608);   // [8388608, 10485760)
    float*          part     = ws + 10485760;                     // step4: 2,621,440 f; step7 reuse: 4,194,304 f (spills into dead S)
    float*          S        = ws + 13107200;                     // 2,097,152 f
    float*          sumdl    = ws + 15204352;                     //   131,072 f
    float*          h0       = ws + 15335424;                     // 2,097,152 f
    float*          xdbc     = ws + 17432576;                     //   163,840 f
    unsigned short* xn_bf    = (unsigned short*)(ws + 17596416);  // 2,097,152 sh
    unsigned short* BTxp     = (unsigned short*)(ws + 18644992);  //   655,360 sh
    unsigned short* BTdt     = (unsigned short*)(ws + 18972672);  //   524,288 sh
    unsigned short* xdbc_dt  = (unsigned short*)(ws + 19234816);  //   131,072 sh
    unsigned short* BT_in    = (unsigned short*)(ws + 19300352);  // 16,777,216 sh (blocked)
    unsigned short* BT_out   = (unsigned short*)(ws + 27688960);  //  8,388,608 sh (blocked)
    // total: 31,883,264 f = 127.5 MB

    // 1a. W_in blocked transpose
    prep_win_kernel<<<2048, 256, 0, stream>>>(W_in, BT_in);
    // 1b. W_out blocked + W_dt + W_xp + RMSNorm
    prep_rest_kernel<<<2400, 256, 0, stream>>>(W_xp, W_dt, W_out, x, wn,
                                               BTxp, BTdt, BT_out, xn_bf);
    // 2. xz = xn @ W_in -> bf16  (128x128, blocked-B: 1KB-linear gload_lds)
    gemm_mfma_kernel<128, 128, 2, 0, 1><<<dim3(N_XZ / 128, L_SEQ / 128), 256, 0, stream>>>(
        xn_bf, BT_in, xz_bf, DMODEL, DMODEL, N_XZ, N_XZ, nullptr);
    // 3. conv + silu -> xs bf16 (8 ch/thread, 16B vector loads)
    conv_silu_kernel<<<(L_SEQ * DINNER / 8) / 256, 256, 0, stream>>>(xz_bf, cw, cb, xs_bf);
    // 4. xdbc = xs @ W_xp  (split-K x16, fp32 partials, row-major B)
    gemm_mfma_kernel<64, 64, 2, 2, 0><<<dim3(3, L_SEQ / 64, SK_XP), 256, 0, stream>>>(
        xs_bf, BTxp, part, DINNER, DINNER / SK_XP, N_XP, N_XP, nullptr);
    reduce_sk_kernel<<<(L_SEQ * N_XP / 4) / 256, 256, 0, stream>>>(part, xdbc, xdbc_dt);
    // 5. delta = softplus(xdbc_dt @ W_dt + b_dt) -> bf16  (zero-LDS direct-reg K=128 GEMM)
    gemm_k128_softplus_kernel<<<dim3(DINNER / 64, L_SEQ / 64), 256, 0, stream>>>(
        xdbc_dt, BTdt, delta_bf, b_dt);
    // 6. selective scan (3 passes, 32 chunks) + gate -> yg bf16 (LDS-staged vector IO)
    scan_pass1<<<dim3(DINNER / 256, NCHUNK), 256, 0, stream>>>(delta_bf, xs_bf, xdbc, A_log, S, sumdl);
    scan_pass2<<<(DINNER * 16) / 256, 256, 0, stream>>>(S, sumdl, A_log, h0);
    scan_pass3<<<dim3(DINNER / 256, NCHUNK), 256, 0, stream>>>(delta_bf, xs_bf, xdbc, xz_bf,
                                                               A_log, Dp, h0, yg_bf);
    // 7. out = yg @ W_out (64x128, blocked-B, split-K x2 -> 512 blocks = 2/CU, fp32 partials)
    gemm_mfma_kernel<64, 128, 2, 2, 1><<<dim3(DMODEL / 128, L_SEQ / 64, 2), 256, 0, stream>>>(
        yg_bf, BT_out, part, DINNER, DINNER / 2, DMODEL, DMODEL, nullptr);
    //    reduce partials + residual x -> out
    reduce2_res_kernel<<<(L_SEQ * DMODEL) / 1024, 256, 0, stream>>>(part, x, out);
}

// Round 12
// 318.305 us; speedup vs baseline: 1.1060x; 1.0157x over previous
//
#include <hip/hip_runtime.h>
#include <math.h>

#define L_SEQ   1024
#define DMODEL  2048
#define DINNER  4096
#define DSTATE  16
#define DTRANK  128
#define N_XZ    (2 * DINNER)            // 8192
#define N_XP    (DTRANK + 2 * DSTATE)   // 160
#define EPS_F   1e-5f
#define NCHUNK  32
#define TCH     32
#define SK_XP   16                      // split-K for xdbc GEMM

using bf16x8 = __attribute__((ext_vector_type(8))) short;
using f32x4  = __attribute__((ext_vector_type(4))) float;

__device__ __forceinline__ float silu_f(float v) {
    return v * (1.0f / (1.0f + __expf(-v)));
}
__device__ __forceinline__ float softplus_f(float v) {
    return (v > 15.0f) ? v : log1pf(__expf(v));
}
__device__ __forceinline__ unsigned short f2bf(float f) {
    unsigned b = __float_as_uint(f);
    return (unsigned short)((b + 0x7FFFu + ((b >> 16) & 1u)) >> 16);
}
__device__ __forceinline__ float bf2f(unsigned short u) {
    return __uint_as_float((unsigned)u << 16);
}

#define GLOAD_LDS(gp, lp) \
    __builtin_amdgcn_global_load_lds((const __attribute__((address_space(1))) void*)(gp), \
                                     (__attribute__((address_space(3))) void*)(lp), 16, 0, 0)

// ================= prep: weight transposes + RMSNorm (merged, R7-verified) =================
__device__ __forceinline__ void transpose_blocked(const float* __restrict__ W,
                                                  unsigned short* __restrict__ BTb,
                                                  int K, int N, int bx, int by,
                                                  unsigned short* Tb) {
    const int tid = threadIdx.x;
    const int n0 = bx * 64, k0 = by * 128;
    #pragma unroll
    for (int i = 0; i < 8; ++i) {
        const int r = i * 16 + (tid >> 4);      // k-row 0..127
        const int c = (tid & 15) * 4;           // n-col 0..60
        float4 v = *(const float4*)&W[(size_t)(k0 + r) * N + n0 + c];
        Tb[(c + 0) * 136 + r] = f2bf(v.x);
        Tb[(c + 1) * 136 + r] = f2bf(v.y);
        Tb[(c + 2) * 136 + r] = f2bf(v.z);
        Tb[(c + 3) * 136 + r] = f2bf(v.w);
    }
    __syncthreads();
    const int wave = tid >> 6, lane = tid & 63;
    const int kblocks = K >> 5;
    #pragma unroll
    for (int t = 0; t < 4; ++t) {
        const int ob = wave * 4 + t;            // 0..15
        const int nb = ob >> 2, kb = ob & 3;
        const int n = nb * 16 + (lane >> 2);    // local n 0..63
        const int k = kb * 32 + (lane & 3) * 8; // local k 0..127
        bf16x8 v = *(const bf16x8*)&Tb[n * 136 + k];
        const size_t blk = (size_t)(((n0 >> 4) + nb)) * kblocks + ((k0 >> 5) + kb);
        *(bf16x8*)&BTb[blk * 512 + (size_t)lane * 8] = v;
    }
}

// Row-major reg-transpose (W_dt -> BTdt). R2-verified.
__device__ __forceinline__ void transpose_fast(const float* __restrict__ W,
                                               unsigned short* __restrict__ BT,
                                               int K, int N, int bx, int by) {
    const int wave = threadIdx.x >> 6, lane = threadIdx.x & 63;
    const int lr = lane >> 3, lc = lane & 7;
    const int k0 = by * 128 + (wave >> 1) * 64 + lr * 8;
    const int n0 = bx * 128 + (wave & 1) * 64 + lc * 8;
    float v[8][8];
    #pragma unroll
    for (int j = 0; j < 8; ++j) {
        float4 a = *(const float4*)&W[(size_t)(k0 + j) * N + n0];
        float4 b = *(const float4*)&W[(size_t)(k0 + j) * N + n0 + 4];
        v[j][0] = a.x; v[j][1] = a.y; v[j][2] = a.z; v[j][3] = a.w;
        v[j][4] = b.x; v[j][5] = b.y; v[j][6] = b.z; v[j][7] = b.w;
    }
    #pragma unroll
    for (int i = 0; i < 8; ++i) {
        bf16x8 o;
        #pragma unroll
        for (int j = 0; j < 8; ++j) o[j] = (short)f2bf(v[j][i]);
        *(bf16x8*)&BT[(size_t)(n0 + i) * K + k0] = o;
    }
}

// Legacy LDS path (only W_xp: N=160; 2.5 MB, conflicts negligible)
__device__ __forceinline__ void transpose_body(const float* __restrict__ W,
                                               unsigned short* __restrict__ BT,
                                               int K, int N, int bx, int by,
                                               unsigned short (*Tl)[72]) {
    const int k0 = by * 64, n0 = bx * 32;
    const int kr = threadIdx.x >> 3;
    const int nc = (threadIdx.x & 7) * 4;
    float4 v0 = *(const float4*)&W[(size_t)(k0 + kr) * N + n0 + nc];
    float4 v1 = *(const float4*)&W[(size_t)(k0 + kr + 32) * N + n0 + nc];
    Tl[nc + 0][kr] = f2bf(v0.x); Tl[nc + 1][kr] = f2bf(v0.y);
    Tl[nc + 2][kr] = f2bf(v0.z); Tl[nc + 3][kr] = f2bf(v0.w);
    Tl[nc + 0][kr + 32] = f2bf(v1.x); Tl[nc + 1][kr + 32] = f2bf(v1.y);
    Tl[nc + 2][kr + 32] = f2bf(v1.z); Tl[nc + 3][kr + 32] = f2bf(v1.w);
    __syncthreads();
    const int n = threadIdx.x >> 3;
    const int k8 = (threadIdx.x & 7) * 8;
    *(bf16x8*)&BT[(size_t)(n0 + n) * K + k0 + k8] = *(const bf16x8*)&Tl[n][k8];
}

__global__ __launch_bounds__(256) void prep_kernel(const float* __restrict__ W_in,
                                                   const float* __restrict__ W_xp,
                                                   const float* __restrict__ W_dt,
                                                   const float* __restrict__ W_out,
                                                   const float* __restrict__ x,
                                                   const float* __restrict__ wn,
                                                   unsigned short* __restrict__ BT_in,
                                                   unsigned short* __restrict__ BTxp,
                                                   unsigned short* __restrict__ BTdt,
                                                   unsigned short* __restrict__ BT_out,
                                                   unsigned short* __restrict__ xn_bf) {
    __shared__ __align__(16) unsigned short Tb[64 * 136];
    __shared__ unsigned short Tl[32][72];
    __shared__ float red[4];
    int b = blockIdx.x;
    if (b < 2048) {                       // W_in blocked: 128 n-tiles x 16 k-tiles
        transpose_blocked(W_in, BT_in, DMODEL, N_XZ, b & 127, b >> 7, Tb);
    } else if (b < 3072) {                // W_out blocked: 32 n-tiles x 32 k-tiles
        b -= 2048;
        transpose_blocked(W_out, BT_out, DINNER, DMODEL, b & 31, b >> 5, Tb);
    } else if (b < 3104) {                // W_dt row-major: K=128, N=4096 (32 tiles)
        b -= 3072;
        transpose_fast(W_dt, BTdt, DTRANK, DINNER, b, 0);
    } else if (b < 3424) {                // W_xp legacy: K=4096, N=160
        b -= 3104;
        transpose_body(W_xp, BTxp, DINNER, N_XP, b % 5, b / 5, Tl);
    } else {                              // RMSNorm rows 0..1023
        const int row = b - 3424;
        const float4* xr = (const float4*)(x + (size_t)row * DMODEL);
        float ss = 0.f;
        float4 v0 = xr[threadIdx.x];
        float4 v1 = xr[threadIdx.x + 256];
        ss += v0.x*v0.x + v0.y*v0.y + v0.z*v0.z + v0.w*v0.w;
        ss += v1.x*v1.x + v1.y*v1.y + v1.z*v1.z + v1.w*v1.w;
        #pragma unroll
        for (int o = 32; o > 0; o >>= 1) ss += __shfl_down(ss, o);
        const int lane = threadIdx.x & 63, wv = threadIdx.x >> 6;
        if (lane == 0) red[wv] = ss;
        __syncthreads();
        if (threadIdx.x == 0) {
            float t = red[0] + red[1] + red[2] + red[3];
            red[0] = rsqrtf(t / (float)DMODEL + EPS_F);
        }
        __syncthreads();
        const float scale = red[0];
        const float4* wr = (const float4*)wn;
        float4 w0 = wr[threadIdx.x];
        float4 w1 = wr[threadIdx.x + 256];
        ushort4 o0, o1;
        o0.x = f2bf(v0.x * scale * w0.x); o0.y = f2bf(v0.y * scale * w0.y);
        o0.z = f2bf(v0.z * scale * w0.z); o0.w = f2bf(v0.w * scale * w0.w);
        o1.x = f2bf(v1.x * scale * w1.x); o1.y = f2bf(v1.y * scale * w1.y);
        o1.z = f2bf(v1.z * scale * w1.z); o1.w = f2bf(v1.w * scale * w1.w);
        unsigned short* outr = xn_bf + (size_t)row * DMODEL;
        *(ushort4*)&outr[threadIdx.x * 4] = o0;
        *(ushort4*)&outr[1024 + threadIdx.x * 4] = o1;
    }
}

// ================= bf16 MFMA GEMM, BK = KC*32 per barrier pair =================
// C(MxN) = A(MxK bf16) @ B^T. BLK=0 row-major BT[N][K]; BLK=1 blocked BT[N/16][K/32][16][32].
// OUTM 0: bf16 plain   OUTM 2: fp32 split-K partial
template <int BM, int BN, int KC, int OUTM, int BLK>
__global__ __launch_bounds__(256) void gemm_mfma_kernel(const unsigned short* __restrict__ A,
                                                        const unsigned short* __restrict__ BT,
                                                        void* __restrict__ Cv,
                                                        int K, int Kc, int ldc, int Ncols,
                                                        const float* __restrict__ aux) {
    constexpr int MT = BM / 32;
    constexpr int NT = BN / 32;
    __shared__ __align__(16) unsigned short Al[KC * BM * 32];
    __shared__ __align__(16) unsigned short Bl[KC * BN * 32];
    const int tid = threadIdx.x;
    const int lane = tid & 63, wave = tid >> 6;
    const int wm = wave >> 1, wn = wave & 1;
    const int bm = blockIdx.y * BM, bn = blockIdx.x * BN;
    const size_t koff = (size_t)blockIdx.z * Kc;
    float* Cf = (float*)Cv;
    if (OUTM == 2) Cf += (size_t)blockIdx.z * (size_t)gridDim.y * BM * ldc;
    const int sr = lane >> 2;
    const int sk = (((lane & 3) ^ ((sr >> 1) & 3))) * 8;
    const int fr = lane & 15;
    const int fq = lane >> 4;
    const int fsw = (fq ^ ((fr >> 1) & 3)) * 8;

    f32x4 acc[MT][NT];
    #pragma unroll
    for (int i = 0; i < MT; ++i)
        #pragma unroll
        for (int j = 0; j < NT; ++j)
            acc[i][j] = (f32x4){0.f, 0.f, 0.f, 0.f};

    for (int k0 = 0; k0 < Kc; k0 += 32 * KC) {
        #pragma unroll
        for (int p = 0; p < KC; ++p) {
            #pragma unroll
            for (int is = wave; is < BM / 16; is += 4)
                GLOAD_LDS(&A[(size_t)(bm + is * 16 + sr) * K + koff + k0 + p * 32 + sk],
                          &Al[p * BM * 32 + is * 512]);
            #pragma unroll
            for (int is = wave; is < BN / 16; is += 4) {
                if (BLK) {
                    const size_t blk = (size_t)((bn >> 4) + is) * (K >> 5)
                                     + ((koff + k0 + p * 32) >> 5);
                    GLOAD_LDS(&BT[blk * 512 + sr * 32 + sk],
                              &Bl[p * BN * 32 + is * 512]);
                } else {
                    GLOAD_LDS(&BT[(size_t)(bn + is * 16 + sr) * K + koff + k0 + p * 32 + sk],
                              &Bl[p * BN * 32 + is * 512]);
                }
            }
        }
        __syncthreads();
        #pragma unroll
        for (int p = 0; p < KC; ++p) {
            bf16x8 af[MT], bfr[NT];
            #pragma unroll
            for (int i = 0; i < MT; ++i)
                af[i] = *(const bf16x8*)&Al[p * BM * 32 + (wm * (BM / 2) + i * 16 + fr) * 32 + fsw];
            #pragma unroll
            for (int j = 0; j < NT; ++j)
                bfr[j] = *(const bf16x8*)&Bl[p * BN * 32 + (wn * (BN / 2) + j * 16 + fr) * 32 + fsw];
            #pragma unroll
            for (int i = 0; i < MT; ++i)
                #pragma unroll
                for (int j = 0; j < NT; ++j)
                    acc[i][j] = __builtin_amdgcn_mfma_f32_16x16x32_bf16(af[i], bfr[j], acc[i][j], 0, 0, 0);
        }
        __syncthreads();
    }

    #pragma unroll
    for (int i = 0; i < MT; ++i) {
        const int row = bm + wm * (BM / 2) + i * 16 + fq * 4;
        #pragma unroll
        for (int j = 0; j < NT; ++j) {
            const int col = bn + wn * (BN / 2) + j * 16 + fr;
            if (col < Ncols) {
                #pragma unroll
                for (int r = 0; r < 4; ++r) {
                    float v = acc[i][j][r];
                    if (OUTM == 0) {
                        ((unsigned short*)Cv)[(size_t)(row + r) * ldc + col] = f2bf(v);
                    } else {
                        Cf[(size_t)(row + r) * ldc + col] = v;
                    }
                }
            }
        }
    }
}

// ================= Depthwise causal conv (k=4) + SiLU, bf16 in/out, 8 ch/thread ==========
__global__ __launch_bounds__(256) void conv_silu_kernel(const unsigned short* __restrict__ xz_bf,
                                                        const float* __restrict__ cw,
                                                        const float* __restrict__ cb,
                                                        unsigned short* __restrict__ xs_bf) {
    const int idx = blockIdx.x * 256 + threadIdx.x;   // over L_SEQ * (DINNER/8)
    const int t = idx >> 9;
    const int c8 = (idx & 511) * 8;
    float acc[8];
    {
        float4 b0 = *(const float4*)&cb[c8];
        float4 b1 = *(const float4*)&cb[c8 + 4];
        acc[0] = b0.x; acc[1] = b0.y; acc[2] = b0.z; acc[3] = b0.w;
        acc[4] = b1.x; acc[5] = b1.y; acc[6] = b1.z; acc[7] = b1.w;
    }
    #pragma unroll
    for (int k = 0; k < 4; ++k) {
        const int tt = t + k - 3;
        if (tt >= 0) {
            bf16x8 xv = *(const bf16x8*)&xz_bf[(size_t)tt * N_XZ + c8];
            float4 w0 = *(const float4*)&cw[k * DINNER + c8];
            float4 w1 = *(const float4*)&cw[k * DINNER + c8 + 4];
            acc[0] = fmaf(bf2f((unsigned short)xv[0]), w0.x, acc[0]);
            acc[1] = fmaf(bf2f((unsigned short)xv[1]), w0.y, acc[1]);
            acc[2] = fmaf(bf2f((unsigned short)xv[2]), w0.z, acc[2]);
            acc[3] = fmaf(bf2f((unsigned short)xv[3]), w0.w, acc[3]);
            acc[4] = fmaf(bf2f((unsigned short)xv[4]), w1.x, acc[4]);
            acc[5] = fmaf(bf2f((unsigned short)xv[5]), w1.y, acc[5]);
            acc[6] = fmaf(bf2f((unsigned short)xv[6]), w1.z, acc[6]);
            acc[7] = fmaf(bf2f((unsigned short)xv[7]), w1.w, acc[7]);
        }
    }
    bf16x8 o;
    #pragma unroll
    for (int q = 0; q < 8; ++q) o[q] = (short)f2bf(silu_f(acc[q]));
    *(bf16x8*)&xs_bf[(size_t)t * DINNER + c8] = o;
}

// ================= reduce SK_XP split-K partials -> xdbc fp32 (+ bf16 dt cols) =================
__global__ __launch_bounds__(256) void reduce_sk_kernel(const float* __restrict__ part,
                                                        float* __restrict__ xdbc,
                                                        unsigned short* __restrict__ xdbc_dt) {
    const int i = (blockIdx.x * 256 + threadIdx.x) * 4;   // row*160 + col, 4-wide
    float4 s = make_float4(0.f, 0.f, 0.f, 0.f);
    #pragma unroll
    for (int c = 0; c < SK_XP; ++c) {
        float4 v = *(const float4*)&part[(size_t)c * (L_SEQ * N_XP) + i];
        s.x += v.x; s.y += v.y; s.z += v.z; s.w += v.w;
    }
    *(float4*)&xdbc[i] = s;
    const int col = i % N_XP;                              // multiple of 4; quad stays in-row
    if (col < DTRANK) {
        ushort4 o;
        o.x = f2bf(s.x); o.y = f2bf(s.y); o.z = f2bf(s.z); o.w = f2bf(s.w);
        *(ushort4*)&xdbc_dt[(i / N_XP) * DTRANK + col] = o;
    }
}

// ============ reduce 2 split-K partials + residual x -> out fp32 (step 7 tail) ============
__global__ __launch_bounds__(256) void reduce2_res_kernel(const float* __restrict__ part,
                                                          const float* __restrict__ x,
                                                          float* __restrict__ out) {
    const size_t i = ((size_t)blockIdx.x * 256 + threadIdx.x) * 4;
    float4 a = *(const float4*)&part[i];
    float4 b = *(const float4*)&part[(size_t)L_SEQ * DMODEL + i];
    float4 r = *(const float4*)&x[i];
    float4 o;
    o.x = a.x + b.x + r.x;
    o.y = a.y + b.y + r.y;
    o.z = a.z + b.z + r.z;
    o.w = a.w + b.w + r.w;
    *(float4*)&out[i] = o;
}

// ================= Selective scan, 3-pass chunked linear recurrence =================
// pass1 FUSED with the delta GEMM: per block (32t x 256d tile), compute
// delta = softplus(xdbc_dt[32x128] @ BTdt[256x128]^T + b_dt) via zero-LDS K=128
// MFMA fragments (k128-verified pattern), write delta to LDS (consumed here) AND
// to delta_bf global (consumed by pass3). Eliminates the separate k128 launch.
__global__ __launch_bounds__(256) void scan_pass1(const unsigned short* __restrict__ xdbc_dt,
                                                  const unsigned short* __restrict__ BTdt,
                                                  const float* __restrict__ b_dt,
                                                  const unsigned short* __restrict__ xs_bf,
                                                  const float* __restrict__ xdbc,
                                                  const float* __restrict__ A_log,
                                                  unsigned short* __restrict__ delta_bf,
                                                  float* __restrict__ S,
                                                  float* __restrict__ sumdl) {
    __shared__ float BC[TCH][32];
    __shared__ __align__(16) unsigned short DL[TCH][256];
    __shared__ __align__(16) unsigned short US[TCH][256];
    const int c = blockIdx.y;
    const int tid = threadIdx.x;
    const int d0 = blockIdx.x * 256;
    const int d = d0 + tid;
    const int t0 = c * TCH;
    const int lane = tid & 63, wave = tid >> 6;
    const int fr = lane & 15, fq = lane >> 4;

    // ---- fused delta GEMM (K=128, zero-LDS fragments) ----
    bf16x8 af[2][4], bfr[4][4];
    #pragma unroll
    for (int i = 0; i < 2; ++i) {
        const unsigned short* Ap = &xdbc_dt[(size_t)(t0 + i * 16 + fr) * DTRANK + fq * 8];
        #pragma unroll
        for (int kc = 0; kc < 4; ++kc) af[i][kc] = *(const bf16x8*)&Ap[kc * 32];
    }
    #pragma unroll
    for (int j = 0; j < 4; ++j) {
        const unsigned short* Bp = &BTdt[(size_t)(d0 + wave * 64 + j * 16 + fr) * DTRANK + fq * 8];
        #pragma unroll
        for (int kc = 0; kc < 4; ++kc) bfr[j][kc] = *(const bf16x8*)&Bp[kc * 32];
    }
    f32x4 acc[2][4];
    #pragma unroll
    for (int i = 0; i < 2; ++i)
        #pragma unroll
        for (int j = 0; j < 4; ++j)
            acc[i][j] = (f32x4){0.f, 0.f, 0.f, 0.f};
    #pragma unroll
    for (int kc = 0; kc < 4; ++kc)
        #pragma unroll
        for (int i = 0; i < 2; ++i)
            #pragma unroll
            for (int j = 0; j < 4; ++j)
                acc[i][j] = __builtin_amdgcn_mfma_f32_16x16x32_bf16(af[i][kc], bfr[j][kc], acc[i][j], 0, 0, 0);
    #pragma unroll
    for (int i = 0; i < 2; ++i) {
        #pragma unroll
        for (int j = 0; j < 4; ++j) {
            const int col = wave * 64 + j * 16 + fr;          // local d 0..255
            const float bc = b_dt[d0 + col];
            #pragma unroll
            for (int r = 0; r < 4; ++r) {
                const int row = i * 16 + fq * 4 + r;          // local t 0..31
                const unsigned short dv = f2bf(softplus_f(acc[i][j][r] + bc));
                DL[row][col] = dv;
                delta_bf[(size_t)(t0 + row) * DINNER + d0 + col] = dv;
            }
        }
    }

    // ---- stage BC + xs tiles ----
    {
        const int tt = tid >> 3, q = tid & 7;
        *(float4*)&BC[tt][q * 4] =
            *(const float4*)&xdbc[(size_t)(t0 + tt) * N_XP + DTRANK + q * 4];
    }
    #pragma unroll
    for (int u = 0; u < 4; ++u) {
        const int l = tid + 256 * u;
        const int r = l >> 5, cc = (l & 31) * 8;
        *(bf16x8*)&US[r][cc] = *(const bf16x8*)&xs_bf[(size_t)(t0 + r) * DINNER + d0 + cc];
    }
    __syncthreads();

    float Aa[16];
    #pragma unroll
    for (int n = 0; n < 16; n += 4) {
        float4 a = *(const float4*)&A_log[(size_t)d * 16 + n];
        Aa[n]     = -__expf(a.x); Aa[n + 1] = -__expf(a.y);
        Aa[n + 2] = -__expf(a.z); Aa[n + 3] = -__expf(a.w);
    }
    float h[16];
    #pragma unroll
    for (int n = 0; n < 16; ++n) h[n] = 0.f;
    float sd = 0.f;
    for (int t = 0; t < TCH; ++t) {
        const float dl = bf2f(DL[t][tid]);
        const float u  = bf2f(US[t][tid]);
        sd += dl;
        const float du = dl * u;
        #pragma unroll
        for (int n = 0; n < 16; ++n)
            h[n] = fmaf(h[n], __expf(dl * Aa[n]), du * BC[t][n]);
    }
    float* Sp = &S[((size_t)c * DINNER + d) * 16];
    #pragma unroll
    for (int n = 0; n < 16; n += 4)
        *(float4*)&Sp[n] = make_float4(h[n], h[n + 1], h[n + 2], h[n + 3]);
    sumdl[c * DINNER + d] = sd;
}

__global__ __launch_bounds__(256) void scan_pass2(const float* __restrict__ S,
                                                  const float* __restrict__ sumdl,
                                                  const float* __restrict__ A_log,
                                                  float* __restrict__ h0) {
    const int i = blockIdx.x * 256 + threadIdx.x;   // d*16 + n
    const int dd = i >> 4;
    const float A = -__expf(A_log[i]);
    float h = 0.f;
    #pragma unroll
    for (int c = 0; c < NCHUNK; ++c) {
        h0[(size_t)c * (DINNER * 16) + i] = h;
        h = h * __expf(A * sumdl[c * DINNER + dd]) + S[(size_t)c * (DINNER * 16) + i];
    }
}

__global__ __launch_bounds__(256) void scan_pass3(const unsigned short* __restrict__ delta_bf,
                                                  const unsigned short* __restrict__ xs_bf,
                                                  const float* __restrict__ xdbc,
                                                  const unsigned short* __restrict__ xz_bf,
                                                  const float* __restrict__ A_log,
                                                  const float* __restrict__ Dp,
                                                  const float* __restrict__ h0,
                                                  unsigned short* __restrict__ yg_bf) {
    __shared__ float BC[TCH][32];
    __shared__ __align__(16) unsigned short DL[TCH][256];
    __shared__ __align__(16) unsigned short US[TCH][256];
    __shared__ __align__(16) unsigned short RS[TCH][256];
    __shared__ __align__(16) unsigned short YG[TCH][256];
    const int c = blockIdx.y;
    const int tid = threadIdx.x;
    const int d0 = blockIdx.x * 256;
    const int d = d0 + tid;
    const int t0 = c * TCH;
    {
        const int tt = tid >> 3, q = tid & 7;
        *(float4*)&BC[tt][q * 4] =
            *(const float4*)&xdbc[(size_t)(t0 + tt) * N_XP + DTRANK + q * 4];
    }
    #pragma unroll
    for (int u = 0; u < 4; ++u) {
        const int l = tid + 256 * u;
        const int r = l >> 5, cc = (l & 31) * 8;
        *(bf16x8*)&DL[r][cc] = *(const bf16x8*)&delta_bf[(size_t)(t0 + r) * DINNER + d0 + cc];
        *(bf16x8*)&US[r][cc] = *(const bf16x8*)&xs_bf[(size_t)(t0 + r) * DINNER + d0 + cc];
        *(bf16x8*)&RS[r][cc] =
            *(const bf16x8*)&xz_bf[(size_t)(t0 + r) * N_XZ + DINNER + d0 + cc];
    }
    __syncthreads();
    float Aa[16];
    #pragma unroll
    for (int n = 0; n < 16; n += 4) {
        float4 a = *(const float4*)&A_log[(size_t)d * 16 + n];
        Aa[n]     = -__expf(a.x); Aa[n + 1] = -__expf(a.y);
        Aa[n + 2] = -__expf(a.z); Aa[n + 3] = -__expf(a.w);
    }
    float h[16];
    const float* h0p = &h0[(size_t)c * (DINNER * 16) + d * 16];
    #pragma unroll
    for (int n = 0; n < 16; n += 4) {
        float4 v = *(const float4*)&h0p[n];
        h[n] = v.x; h[n + 1] = v.y; h[n + 2] = v.z; h[n + 3] = v.w;
    }
    const float Dd = Dp[d];
    for (int t = 0; t < TCH; ++t) {
        const float dl = bf2f(DL[t][tid]);
        const float u  = bf2f(US[t][tid]);
        const float du = dl * u;
        float y = 0.f;
        #pragma unroll
        for (int n = 0; n < 16; ++n) {
            h[n] = fmaf(h[n], __expf(dl * Aa[n]), du * BC[t][n]);
            y = fmaf(h[n], BC[t][16 + n], y);
        }
        const float res = bf2f(RS[t][tid]);
        YG[t][tid] = f2bf((y + u * Dd) * silu_f(res));
    }
    __syncthreads();
    #pragma unroll
    for (int u = 0; u < 4; ++u) {
        const int l = tid + 256 * u;
        const int r = l >> 5, cc = (l & 31) * 8;
        *(bf16x8*)&yg_bf[(size_t)(t0 + r) * DINNER + d0 + cc] = *(const bf16x8*)&YG[r][cc];
    }
}

extern "C" void kernel_launch(void* const* d_in, const int* in_sizes, int n_in,
                              void* d_out, int out_size, void* d_ws, size_t ws_size,
                              hipStream_t stream) {
    const float* x     = (const float*)d_in[0];
    const float* wn    = (const float*)d_in[1];
    const float* W_in  = (const float*)d_in[2];
    const float* cw    = (const float*)d_in[3];
    const float* cb    = (const float*)d_in[4];
    const float* W_xp  = (const float*)d_in[5];
    const float* W_dt  = (const float*)d_in[6];
    const float* b_dt  = (const float*)d_in[7];
    const float* A_log = (const float*)d_in[8];
    const float* Dp    = (const float*)d_in[9];
    const float* W_out = (const float*)d_in[10];
    float* out = (float*)d_out;

    float* ws = (float*)d_ws;                                     // offsets in floats
    unsigned short* xz_bf    = (unsigned short*)ws;               // [0, 4194304)
    unsigned short* xs_bf    = (unsigned short*)(ws + 4194304);   // [4194304, 6291456)
    unsigned short* yg_bf    = (unsigned short*)(ws + 6291456);   // [6291456, 8388608)
    unsigned short* delta_bf = (unsigned short*)(ws + 8388608);   // [8388608, 10485760)
    float*          part     = ws + 10485760;                     // step4: 2,621,440 f; step7 reuse: 4,194,304 f (spills into dead S)
    float*          S        = ws + 13107200;                     // 2,097,152 f
    float*          sumdl    = ws + 15204352;                     //   131,072 f
    float*          h0       = ws + 15335424;                     // 2,097,152 f
    float*          xdbc     = ws + 17432576;                     //   163,840 f
    unsigned short* xn_bf    = (unsigned short*)(ws + 17596416);  // 2,097,152 sh
    unsigned short* BTxp     = (unsigned short*)(ws + 18644992);  //   655,360 sh
    unsigned short* BTdt     = (unsigned short*)(ws + 18972672);  //   524,288 sh
    unsigned short* xdbc_dt  = (unsigned short*)(ws + 19234816);  //   131,072 sh
    unsigned short* BT_in    = (unsigned short*)(ws + 19300352);  // 16,777,216 sh (blocked)
    unsigned short* BT_out   = (unsigned short*)(ws + 27688960);  //  8,388,608 sh (blocked)
    // total: 31,883,264 f = 127.5 MB

    // 1. prep (merged): W_in/W_out blocked + W_dt fast + W_xp legacy + RMSNorm
    prep_kernel<<<4448, 256, 0, stream>>>(W_in, W_xp, W_dt, W_out, x, wn,
                                          BT_in, BTxp, BTdt, BT_out, xn_bf);
    // 2. xz = xn @ W_in -> bf16  (128x128, blocked-B: 1KB-linear gload_lds)
    gemm_mfma_kernel<128, 128, 2, 0, 1><<<dim3(N_XZ / 128, L_SEQ / 128), 256, 0, stream>>>(
        xn_bf, BT_in, xz_bf, DMODEL, DMODEL, N_XZ, N_XZ, nullptr);
    // 3. conv + silu -> xs bf16 (8 ch/thread, 16B vector loads)
    conv_silu_kernel<<<(L_SEQ * DINNER / 8) / 256, 256, 0, stream>>>(xz_bf, cw, cb, xs_bf);
    // 4. xdbc = xs @ W_xp  (split-K x16, fp32 partials, row-major B)
    gemm_mfma_kernel<64, 64, 2, 2, 0><<<dim3(3, L_SEQ / 64, SK_XP), 256, 0, stream>>>(
        xs_bf, BTxp, part, DINNER, DINNER / SK_XP, N_XP, N_XP, nullptr);
    reduce_sk_kernel<<<(L_SEQ * N_XP / 4) / 256, 256, 0, stream>>>(part, xdbc, xdbc_dt);
    // 5+6a. scan pass1 with FUSED delta GEMM (k128 launch eliminated)
    scan_pass1<<<dim3(DINNER / 256, NCHUNK), 256, 0, stream>>>(
        xdbc_dt, BTdt, b_dt, xs_bf, xdbc, A_log, delta_bf, S, sumdl);
    scan_pass2<<<(DINNER * 16) / 256, 256, 0, stream>>>(S, sumdl, A_log, h0);
    scan_pass3<<<dim3(DINNER / 256, NCHUNK), 256, 0, stream>>>(delta_bf, xs_bf, xdbc, xz_bf,
                                                               A_log, Dp, h0, yg_bf);
    // 7. out = yg @ W_out (64x128, blocked-B, split-K x2 -> 512 blocks = 2/CU, fp32 partials)
    gemm_mfma_kernel<64, 128, 2, 2, 1><<<dim3(DMODEL / 128, L_SEQ / 64, 2), 256, 0, stream>>>(
        yg_bf, BT_out, part, DINNER, DINNER / 2, DMODEL, DMODEL, nullptr);
    //    reduce partials + residual x -> out
    reduce2_res_kernel<<<(L_SEQ * DMODEL) / 1024, 256, 0, stream>>>(part, x, out);
}